// Round 1
// baseline (1141.810 us; speedup 1.0000x reference)
//
#include <hip/hip_runtime.h>
#include <math.h>

#define HIDDEN 1024
#define NH 16
#define NKV 4
#define HD 64
#define BS_ 2
#define SEQ_ 2048
#define WIN 1534   // allowed iff k - q <= 1534 (reference: triu(-inf, k=1535))

// ---------------- GEMM: C[M,N] = A[M,K] * B[N,K]^T + bias ----------------
// fp32, 64x64 tile, BK=16, 256 threads, 4x4 microtile per thread.
__global__ __launch_bounds__(256) void gemm_nt_bias(
    const float* __restrict__ A, const float* __restrict__ B,
    const float* __restrict__ bias, float* __restrict__ C,
    int M, int N, int K)
{
    const int BK = 16;
    __shared__ float sA[16][64];   // [k][m]
    __shared__ float sB[16][64];   // [k][n]
    int tid = threadIdx.x;
    int tx = tid & 15, ty = tid >> 4;
    int m0 = blockIdx.y * 64, n0 = blockIdx.x * 64;
    int lrow = tid >> 2;          // 0..63
    int lcol = (tid & 3) * 4;     // 0,4,8,12
    float acc[4][4] = {};
    const float* Ap = A + (size_t)(m0 + lrow) * K + lcol;
    const float* Bp = B + (size_t)(n0 + lrow) * K + lcol;
    for (int k0 = 0; k0 < K; k0 += BK) {
        float4 a4 = *(const float4*)(Ap + k0);
        float4 b4 = *(const float4*)(Bp + k0);
        sA[lcol+0][lrow]=a4.x; sA[lcol+1][lrow]=a4.y; sA[lcol+2][lrow]=a4.z; sA[lcol+3][lrow]=a4.w;
        sB[lcol+0][lrow]=b4.x; sB[lcol+1][lrow]=b4.y; sB[lcol+2][lrow]=b4.z; sB[lcol+3][lrow]=b4.w;
        __syncthreads();
        #pragma unroll
        for (int kk = 0; kk < BK; ++kk) {
            float4 av = *(const float4*)&sA[kk][ty*4];
            float4 bv = *(const float4*)&sB[kk][tx*4];
            float a_[4] = {av.x, av.y, av.z, av.w};
            float b_[4] = {bv.x, bv.y, bv.z, bv.w};
            #pragma unroll
            for (int i = 0; i < 4; ++i)
                #pragma unroll
                for (int j = 0; j < 4; ++j)
                    acc[i][j] += a_[i] * b_[j];
        }
        __syncthreads();
    }
    float4 bv4 = make_float4(0.f, 0.f, 0.f, 0.f);
    if (bias) bv4 = *(const float4*)&bias[n0 + tx*4];
    #pragma unroll
    for (int i = 0; i < 4; ++i) {
        int m = m0 + ty*4 + i;
        float4 c4 = make_float4(acc[i][0] + bv4.x, acc[i][1] + bv4.y,
                                acc[i][2] + bv4.z, acc[i][3] + bv4.w);
        *(float4*)&C[(size_t)m * N + n0 + tx*4] = c4;
    }
}

// ---------------- RoPE (in-place), x: [B][S][nheads][64] ----------------
__global__ void rope_kernel(float* __restrict__ x, int nheads) {
    int idx = blockIdx.x * blockDim.x + threadIdx.x;
    int j = idx & 31;
    int rest = idx >> 5;                 // (b*SEQ + s)*nheads + h
    int s = (rest / nheads) % SEQ_;
    float inv = powf(10000.0f, -(float)j * (1.0f / 32.0f));
    float ang = (float)s * inv;
    float sn, cs;
    sincosf(ang, &sn, &cs);
    float* p = x + (size_t)rest * HD;
    float x0 = p[j], x1 = p[j + 32];
    p[j]      = x0 * cs - x1 * sn;
    p[j + 32] = x0 * sn + x1 * cs;
}

// ---------------- Flash-style attention ----------------
// grid: (SEQ/64, BS*NH). 256 threads = 4 waves; wave w owns query rows
// [w*16, w*16+16); lane = quad(row) * 4 + sub; sub owns dims [sub*16, +16).
__global__ __launch_bounds__(256) void attn_kernel(
    const float* __restrict__ Q, const float* __restrict__ K,
    const float* __restrict__ V, const float* __restrict__ amask,
    float* __restrict__ O)
{
    __shared__ float sKT[64][68];   // [dim][key], pad 68 keeps b128 align, 2-way banks
    __shared__ float sV[64][64];    // [key][dim]
    __shared__ float sP[64][65];    // [row][key], pad 65 -> 2-way writes, bcast reads
    __shared__ float sAm[64];
    int tid = threadIdx.x;
    int lane = tid & 63;
    int wave = tid >> 6;
    int sub = lane & 3;
    int row = wave * 16 + (lane >> 2);
    int qb = blockIdx.x;
    int bh = blockIdx.y;
    int b = bh >> 4, h = bh & 15;
    int hk = h >> 2;                 // GQA: 4 heads per kv head
    int q0 = qb * 64;
    int qg = q0 + row;

    float qreg[64];
    {
        const float* qp = Q + ((size_t)(b * SEQ_ + qg) * NH + h) * HD;
        #pragma unroll
        for (int i = 0; i < 16; ++i) {
            float4 v4 = *(const float4*)(qp + 4 * i);
            qreg[4*i] = v4.x; qreg[4*i+1] = v4.y; qreg[4*i+2] = v4.z; qreg[4*i+3] = v4.w;
        }
    }
    float o[16];
    #pragma unroll
    for (int i = 0; i < 16; ++i) o[i] = 0.f;
    float mrun = -INFINITY, lrun = 0.f;

    int nk = min(SEQ_, q0 + 64 + WIN);   // number of keys any row in block may see
    int nkb = (nk + 63) >> 6;

    for (int kb = 0; kb < nkb; ++kb) {
        int k_base = kb * 64;
        #pragma unroll
        for (int i = 0; i < 4; ++i) {
            int idx = tid + i * 256;
            int kk = idx >> 4;
            int c4 = (idx & 15) * 4;
            int kg = k_base + kk;
            const float* kp = K + ((size_t)(b * SEQ_ + kg) * NKV + hk) * HD + c4;
            float4 k4 = *(const float4*)kp;
            sKT[c4+0][kk] = k4.x; sKT[c4+1][kk] = k4.y;
            sKT[c4+2][kk] = k4.z; sKT[c4+3][kk] = k4.w;
            const float* vp = V + ((size_t)(b * SEQ_ + kg) * NKV + hk) * HD + c4;
            *(float4*)&sV[kk][c4] = *(const float4*)vp;
        }
        if (tid < 64) sAm[tid] = amask[b * SEQ_ + k_base + tid] * -10000.0f;
        __syncthreads();

        // scores for this lane's 16 keys: kk = sub*16 + t
        float sc[16];
        #pragma unroll
        for (int t = 0; t < 16; ++t) sc[t] = 0.f;
        #pragma unroll
        for (int d = 0; d < 64; ++d) {
            float qd = qreg[d];
            #pragma unroll
            for (int g = 0; g < 4; ++g) {
                float4 k4 = *(const float4*)&sKT[d][sub * 16 + 4 * g];
                sc[4*g+0] += qd * k4.x; sc[4*g+1] += qd * k4.y;
                sc[4*g+2] += qd * k4.z; sc[4*g+3] += qd * k4.w;
            }
        }
        #pragma unroll
        for (int t = 0; t < 16; ++t) {
            int kk = sub * 16 + t;
            int kg = k_base + kk;
            float s = sc[t] * 0.125f + sAm[kk];
            sc[t] = (kg - qg <= WIN) ? s : -INFINITY;
        }
        // online softmax (reduce across the 4 lanes of this row)
        float bm = sc[0];
        #pragma unroll
        for (int t = 1; t < 16; ++t) bm = fmaxf(bm, sc[t]);
        bm = fmaxf(bm, __shfl_xor(bm, 1));
        bm = fmaxf(bm, __shfl_xor(bm, 2));
        float mnew = fmaxf(mrun, bm);
        float alpha = __expf(mrun - mnew);   // first block: exp(-inf)=0
        float ps = 0.f;
        #pragma unroll
        for (int t = 0; t < 16; ++t) {
            float p = __expf(sc[t] - mnew);
            sP[row][sub * 16 + t] = p;
            ps += p;
        }
        ps += __shfl_xor(ps, 1);
        ps += __shfl_xor(ps, 2);
        lrun = lrun * alpha + ps;
        mrun = mnew;
        #pragma unroll
        for (int i = 0; i < 16; ++i) o[i] *= alpha;
        __syncthreads();   // defensive: sP same-wave RAW + keeps waves together

        #pragma unroll
        for (int k = 0; k < 64; ++k) {
            float p = sP[row][k];
            #pragma unroll
            for (int g = 0; g < 4; ++g) {
                float4 v4 = *(const float4*)&sV[k][sub * 16 + 4 * g];
                o[4*g+0] += p * v4.x; o[4*g+1] += p * v4.y;
                o[4*g+2] += p * v4.z; o[4*g+3] += p * v4.w;
            }
        }
        __syncthreads();   // protect sK/sV before next tile load
    }
    float invl = 1.0f / lrun;
    float* op = O + ((size_t)(b * SEQ_ + qg) * NH + h) * HD + sub * 16;
    #pragma unroll
    for (int i = 0; i < 16; ++i) op[i] = o[i] * invl;
}

extern "C" void kernel_launch(void* const* d_in, const int* in_sizes, int n_in,
                              void* d_out, int out_size, void* d_ws, size_t ws_size,
                              hipStream_t stream) {
    const float* X  = (const float*)d_in[0];
    const float* am = (const float*)d_in[1];
    const float* Wq = (const float*)d_in[2];
    const float* bq = (const float*)d_in[3];
    const float* Wk = (const float*)d_in[4];
    const float* bk = (const float*)d_in[5];
    const float* Wv = (const float*)d_in[6];
    const float* bv = (const float*)d_in[7];
    const float* Wo = (const float*)d_in[8];
    float* out = (float*)d_out;

    const int M = BS_ * SEQ_;            // 4096
    float* ws = (float*)d_ws;
    float* Qb = ws;                           // M*1024
    float* Kb = Qb + (size_t)M * HIDDEN;      // M*256
    float* Vb = Kb + (size_t)M * (NKV * HD);  // M*256
    float* Ab = Vb + (size_t)M * (NKV * HD);  // M*1024

    dim3 blk(256);
    gemm_nt_bias<<<dim3(HIDDEN / 64, M / 64), blk, 0, stream>>>(X, Wq, bq, Qb, M, HIDDEN, HIDDEN);
    gemm_nt_bias<<<dim3((NKV * HD) / 64, M / 64), blk, 0, stream>>>(X, Wk, bk, Kb, M, NKV * HD, HIDDEN);
    gemm_nt_bias<<<dim3((NKV * HD) / 64, M / 64), blk, 0, stream>>>(X, Wv, bv, Vb, M, NKV * HD, HIDDEN);
    rope_kernel<<<dim3((M * NH * 32) / 256), blk, 0, stream>>>(Qb, NH);
    rope_kernel<<<dim3((M * NKV * 32) / 256), blk, 0, stream>>>(Kb, NKV);
    attn_kernel<<<dim3(SEQ_ / 64, BS_ * NH), blk, 0, stream>>>(Qb, Kb, Vb, am, Ab);
    gemm_nt_bias<<<dim3(HIDDEN / 64, M / 64), blk, 0, stream>>>(Ab, Wo, nullptr, out, M, HIDDEN, HIDDEN);
}

// Round 2
// 570.534 us; speedup vs baseline: 2.0013x; 2.0013x over previous
//
#include <hip/hip_runtime.h>
#include <math.h>

#define HIDDEN 1024
#define NH 16
#define NKV 4
#define HD 64
#define BS_ 2
#define SEQ_ 2048
#define WIN 1534   // allowed iff k - q <= 1534

typedef unsigned short u16;
typedef short short8 __attribute__((ext_vector_type(8)));
typedef float f32x4 __attribute__((ext_vector_type(4)));
typedef u16 u16x8 __attribute__((ext_vector_type(8)));

__device__ __forceinline__ u16 f2bf(float f) {
    unsigned u = __float_as_uint(f);
    u += 0x7fff + ((u >> 16) & 1);      // RNE
    return (u16)(u >> 16);
}

// ---------------- GEMM: C[M,N] = A[M,K] * B[N,K]^T + bias (fp32) ----------------
__global__ __launch_bounds__(256) void gemm_nt_bias(
    const float* __restrict__ A, const float* __restrict__ B,
    const float* __restrict__ bias, float* __restrict__ C,
    int M, int N, int K)
{
    const int BK = 16;
    __shared__ float sA[16][64];
    __shared__ float sB[16][64];
    int tid = threadIdx.x;
    int tx = tid & 15, ty = tid >> 4;
    int m0 = blockIdx.y * 64, n0 = blockIdx.x * 64;
    int lrow = tid >> 2;
    int lcol = (tid & 3) * 4;
    float acc[4][4] = {};
    const float* Ap = A + (size_t)(m0 + lrow) * K + lcol;
    const float* Bp = B + (size_t)(n0 + lrow) * K + lcol;
    for (int k0 = 0; k0 < K; k0 += BK) {
        float4 a4 = *(const float4*)(Ap + k0);
        float4 b4 = *(const float4*)(Bp + k0);
        sA[lcol+0][lrow]=a4.x; sA[lcol+1][lrow]=a4.y; sA[lcol+2][lrow]=a4.z; sA[lcol+3][lrow]=a4.w;
        sB[lcol+0][lrow]=b4.x; sB[lcol+1][lrow]=b4.y; sB[lcol+2][lrow]=b4.z; sB[lcol+3][lrow]=b4.w;
        __syncthreads();
        #pragma unroll
        for (int kk = 0; kk < BK; ++kk) {
            float4 av = *(const float4*)&sA[kk][ty*4];
            float4 bv = *(const float4*)&sB[kk][tx*4];
            float a_[4] = {av.x, av.y, av.z, av.w};
            float b_[4] = {bv.x, bv.y, bv.z, bv.w};
            #pragma unroll
            for (int i = 0; i < 4; ++i)
                #pragma unroll
                for (int j = 0; j < 4; ++j)
                    acc[i][j] += a_[i] * b_[j];
        }
        __syncthreads();
    }
    float4 bv4 = make_float4(0.f, 0.f, 0.f, 0.f);
    if (bias) bv4 = *(const float4*)&bias[n0 + tx*4];
    #pragma unroll
    for (int i = 0; i < 4; ++i) {
        int m = m0 + ty*4 + i;
        float4 c4 = make_float4(acc[i][0] + bv4.x, acc[i][1] + bv4.y,
                                acc[i][2] + bv4.z, acc[i][3] + bv4.w);
        *(float4*)&C[(size_t)m * N + n0 + tx*4] = c4;
    }
}

// ---- RoPE + cast + relayout: in [b][s][nh][64] f32 -> out [b][nh][s][64] bf16 ----
__global__ void pack_rope(const float* __restrict__ in, u16* __restrict__ out, int nheads) {
    int idx = blockIdx.x * blockDim.x + threadIdx.x;
    int j = idx & 31;
    int rest = idx >> 5;                 // (b*SEQ + s)*nh + h
    int h = rest % nheads;
    int bs = rest / nheads;
    int s = bs % SEQ_;
    int b = bs / SEQ_;
    const float* p = in + (size_t)rest * HD;
    float x0 = p[j], x1 = p[j + 32];
    float inv = powf(10000.0f, -(float)j * (1.0f / 32.0f));
    float sn, cs;
    sincosf((float)s * inv, &sn, &cs);
    u16* q = out + ((size_t)(b * nheads + h) * SEQ_ + s) * HD;
    q[j]      = f2bf(x0 * cs - x1 * sn);
    q[j + 32] = f2bf(x0 * sn + x1 * cs);
}

// ---- V transpose+cast: in [b][s][4][64] f32 -> out [b][4][64][SEQ] bf16 ----
__global__ __launch_bounds__(256) void pack_vT(const float* __restrict__ V, u16* __restrict__ out) {
    __shared__ float sT[64][65];
    int s0 = blockIdx.x * 64;
    int b = blockIdx.y >> 2, hk = blockIdx.y & 3;
    int t = threadIdx.x;
    int sl = t >> 2;
    int c0 = (t & 3) * 16;
    const float* src = V + ((size_t)(b * SEQ_ + s0 + sl) * NKV + hk) * HD + c0;
    #pragma unroll
    for (int i = 0; i < 4; ++i) {
        float4 v4 = *(const float4*)(src + i * 4);
        sT[sl][c0 + i*4 + 0] = v4.x; sT[sl][c0 + i*4 + 1] = v4.y;
        sT[sl][c0 + i*4 + 2] = v4.z; sT[sl][c0 + i*4 + 3] = v4.w;
    }
    __syncthreads();
    int d = t & 63, sc = (t >> 6) * 16;
    u16* dst = out + ((size_t)(b * NKV + hk) * HD + d) * SEQ_ + s0 + sc;
    u16 tmp[16];
    #pragma unroll
    for (int i = 0; i < 16; ++i) tmp[i] = f2bf(sT[sc + i][d]);
    *(u16x8*)dst       = *(u16x8*)&tmp[0];
    *(u16x8*)(dst + 8) = *(u16x8*)&tmp[8];
}

// ---------------- MFMA flash attention ----------------
// grid (SEQ/64, BS*NH), 256 thr = 4 waves; wave owns 16 q-rows.
// mfma 16x16x32 bf16. A[m=lane&15][k=(lane>>4)*8+j]; B[k=(lane>>4)*8+j][n=lane&15];
// C/D: col=lane&15, row=(lane>>4)*4+reg (m89-verified).
__global__ __launch_bounds__(256) void attn_mfma(
    const u16* __restrict__ Qp, const u16* __restrict__ Kp,
    const u16* __restrict__ Vtp, const float* __restrict__ amask,
    float* __restrict__ Ab)
{
    __shared__ u16 sQ[64 * 72];
    __shared__ u16 sK[64 * 72];
    __shared__ u16 sVT[64 * 72];
    __shared__ u16 sP[4][16 * 72];
    __shared__ float sAm[64];
    int tid = threadIdx.x;
    int lane = tid & 63, wave = tid >> 6;
    int col = lane & 15, l4 = lane >> 4;
    int qb = blockIdx.x, bh = blockIdx.y;
    int b = bh >> 4, h = bh & 15, hk = h >> 2;
    int q0 = qb * 64;

    const u16* Qbase = Qp + ((size_t)(b * NH + h) * SEQ_ + q0) * HD;
    #pragma unroll
    for (int i = 0; i < 2; ++i) {
        int idx = tid + i * 256;
        int r_ = idx >> 3, seg = idx & 7;
        *(short8*)&sQ[r_ * 72 + seg * 8] = *(const short8*)(Qbase + r_ * HD + seg * 8);
    }
    __syncthreads();
    short8 qa0 = *(short8*)&sQ[(wave * 16 + col) * 72 + l4 * 8];
    short8 qa1 = *(short8*)&sQ[(wave * 16 + col) * 72 + 32 + l4 * 8];

    f32x4 O[4] = {{0.f,0.f,0.f,0.f},{0.f,0.f,0.f,0.f},{0.f,0.f,0.f,0.f},{0.f,0.f,0.f,0.f}};
    float mrun[4], lrun[4];
    #pragma unroll
    for (int r = 0; r < 4; ++r) { mrun[r] = -INFINITY; lrun[r] = 0.f; }

    const u16* Kbase = Kp + (size_t)(b * NKV + hk) * SEQ_ * HD;
    const u16* Vbase = Vtp + (size_t)(b * NKV + hk) * HD * SEQ_;
    int nk = min(SEQ_, q0 + 64 + WIN);
    int nkb = (nk + 63) >> 6;
    int qg = q0 + wave * 16 + l4 * 4;   // +r

    for (int kb = 0; kb < nkb; ++kb) {
        int k0 = kb * 64;
        #pragma unroll
        for (int i = 0; i < 2; ++i) {
            int idx = tid + i * 256;
            int r_ = idx >> 3, seg = idx & 7;
            *(short8*)&sK[r_ * 72 + seg * 8] =
                *(const short8*)(Kbase + (size_t)(k0 + r_) * HD + seg * 8);
            *(short8*)&sVT[r_ * 72 + seg * 8] =
                *(const short8*)(Vbase + (size_t)r_ * SEQ_ + k0 + seg * 8);
        }
        if (tid < 64) sAm[tid] = amask[b * SEQ_ + k0 + tid] * -10000.0f;
        __syncthreads();

        f32x4 S[4] = {{0.f,0.f,0.f,0.f},{0.f,0.f,0.f,0.f},{0.f,0.f,0.f,0.f},{0.f,0.f,0.f,0.f}};
        #pragma unroll
        for (int t = 0; t < 4; ++t) {
            short8 kf0 = *(short8*)&sK[(t * 16 + col) * 72 + l4 * 8];
            short8 kf1 = *(short8*)&sK[(t * 16 + col) * 72 + 32 + l4 * 8];
            S[t] = __builtin_amdgcn_mfma_f32_16x16x32_bf16(qa0, kf0, S[t], 0, 0, 0);
            S[t] = __builtin_amdgcn_mfma_f32_16x16x32_bf16(qa1, kf1, S[t], 0, 0, 0);
        }

        float am_t[4];
        #pragma unroll
        for (int t = 0; t < 4; ++t) am_t[t] = sAm[t * 16 + col];
        float sc[4][4];   // [r][t]
        #pragma unroll
        for (int t = 0; t < 4; ++t)
            #pragma unroll
            for (int r = 0; r < 4; ++r) {
                float v = S[t][r] * 0.125f + am_t[t];
                int kg = k0 + t * 16 + col;
                sc[r][t] = (kg - (qg + r) <= WIN) ? v : -INFINITY;
            }
        float al[4];
        #pragma unroll
        for (int r = 0; r < 4; ++r) {
            float bm = fmaxf(fmaxf(sc[r][0], sc[r][1]), fmaxf(sc[r][2], sc[r][3]));
            bm = fmaxf(bm, __shfl_xor(bm, 1));
            bm = fmaxf(bm, __shfl_xor(bm, 2));
            bm = fmaxf(bm, __shfl_xor(bm, 4));
            bm = fmaxf(bm, __shfl_xor(bm, 8));
            float mnew = fmaxf(mrun[r], bm);
            al[r] = __expf(mrun[r] - mnew);
            float ps = 0.f;
            #pragma unroll
            for (int t = 0; t < 4; ++t) {
                float p = __expf(sc[r][t] - mnew);
                ps += p;
                sP[wave][(l4 * 4 + r) * 72 + t * 16 + col] = f2bf(p);
            }
            ps += __shfl_xor(ps, 1);
            ps += __shfl_xor(ps, 2);
            ps += __shfl_xor(ps, 4);
            ps += __shfl_xor(ps, 8);
            lrun[r] = lrun[r] * al[r] + ps;
            mrun[r] = mnew;
        }
        #pragma unroll
        for (int dt = 0; dt < 4; ++dt)
            #pragma unroll
            for (int r = 0; r < 4; ++r) O[dt][r] *= al[r];
        __syncthreads();   // sP visible to own wave (conservative) before PV reads

        short8 pa0 = *(short8*)&sP[wave][col * 72 + l4 * 8];
        short8 pa1 = *(short8*)&sP[wave][col * 72 + 32 + l4 * 8];
        #pragma unroll
        for (int dt = 0; dt < 4; ++dt) {
            short8 vf0 = *(short8*)&sVT[(dt * 16 + col) * 72 + l4 * 8];
            short8 vf1 = *(short8*)&sVT[(dt * 16 + col) * 72 + 32 + l4 * 8];
            O[dt] = __builtin_amdgcn_mfma_f32_16x16x32_bf16(pa0, vf0, O[dt], 0, 0, 0);
            O[dt] = __builtin_amdgcn_mfma_f32_16x16x32_bf16(pa1, vf1, O[dt], 0, 0, 0);
        }
        __syncthreads();   // protect sK/sVT before restage
    }
    float inv[4];
    #pragma unroll
    for (int r = 0; r < 4; ++r) inv[r] = 1.0f / lrun[r];
    #pragma unroll
    for (int dt = 0; dt < 4; ++dt)
        #pragma unroll
        for (int r = 0; r < 4; ++r) {
            int s = q0 + wave * 16 + l4 * 4 + r;
            Ab[((size_t)(b * SEQ_ + s) * NH + h) * HD + dt * 16 + col] = O[dt][r] * inv[r];
        }
}

extern "C" void kernel_launch(void* const* d_in, const int* in_sizes, int n_in,
                              void* d_out, int out_size, void* d_ws, size_t ws_size,
                              hipStream_t stream) {
    const float* X  = (const float*)d_in[0];
    const float* am = (const float*)d_in[1];
    const float* Wq = (const float*)d_in[2];
    const float* bq = (const float*)d_in[3];
    const float* Wk = (const float*)d_in[4];
    const float* bk = (const float*)d_in[5];
    const float* Wv = (const float*)d_in[6];
    const float* bv = (const float*)d_in[7];
    const float* Wo = (const float*)d_in[8];
    float* out = (float*)d_out;

    const int M = BS_ * SEQ_;            // 4096
    const int KV = NKV * HD;             // 256
    float* Qb = (float*)d_ws;                      // M*1024 f32 (16MB)
    float* Kb = Qb + (size_t)M * HIDDEN;           // M*256
    float* Vb = Kb + (size_t)M * KV;               // M*256
    u16*  Qp  = (u16*)(Vb + (size_t)M * KV);       // M*1024 bf16
    u16*  Kp  = Qp + (size_t)M * HIDDEN;           // M*256
    u16*  Vtp = Kp + (size_t)M * KV;               // M*256
    float* Ab = Qb;  // alias: attn output reuses Qb (Qb consumed by pack_rope)

    dim3 blk(256);
    gemm_nt_bias<<<dim3(HIDDEN / 64, M / 64), blk, 0, stream>>>(X, Wq, bq, Qb, M, HIDDEN, HIDDEN);
    gemm_nt_bias<<<dim3(KV / 64, M / 64), blk, 0, stream>>>(X, Wk, bk, Kb, M, KV, HIDDEN);
    gemm_nt_bias<<<dim3(KV / 64, M / 64), blk, 0, stream>>>(X, Wv, bv, Vb, M, KV, HIDDEN);
    pack_rope<<<dim3((M * NH * 32) / 256), blk, 0, stream>>>(Qb, Qp, NH);
    pack_rope<<<dim3((M * NKV * 32) / 256), blk, 0, stream>>>(Kb, Kp, NKV);
    pack_vT<<<dim3(SEQ_ / 64, BS_ * NKV), blk, 0, stream>>>(Vb, Vtp);
    attn_mfma<<<dim3(SEQ_ / 64, BS_ * NH), blk, 0, stream>>>(Qp, Kp, Vtp, am, Ab);
    gemm_nt_bias<<<dim3(HIDDEN / 64, M / 64), blk, 0, stream>>>(Ab, Wo, nullptr, out, M, HIDDEN, HIDDEN);
}

// Round 3
// 268.485 us; speedup vs baseline: 4.2528x; 2.1250x over previous
//
#include <hip/hip_runtime.h>
#include <math.h>

#define HIDDEN 1024
#define NH 16
#define NKV 4
#define HD 64
#define BS_ 2
#define SEQ_ 2048
#define WIN 1534   // allowed iff k - q <= 1534

typedef unsigned short u16;
typedef short short8 __attribute__((ext_vector_type(8)));
typedef float f32x4 __attribute__((ext_vector_type(4)));
typedef u16 u16x4 __attribute__((ext_vector_type(4)));
typedef u16 u16x8 __attribute__((ext_vector_type(8)));

__device__ __forceinline__ u16 f2bf(float f) {
    unsigned u = __float_as_uint(f);
    u += 0x7fff + ((u >> 16) & 1);      // RNE
    return (u16)(u >> 16);
}

__device__ __forceinline__ void async_ld16(const u16* g, u16* l) {
    // 16B per lane; LDS dest = wave-uniform base + lane*16 (m97/m104 semantics)
    __builtin_amdgcn_global_load_lds(
        (const __attribute__((address_space(1))) unsigned int*)g,
        (__attribute__((address_space(3))) unsigned int*)l, 16, 0, 0);
}

// ---------------- cast fp32 -> bf16 for X and the 4 weights ----------------
__global__ __launch_bounds__(256) void cast5(
    const float* __restrict__ x, const float* __restrict__ wq,
    const float* __restrict__ wk, const float* __restrict__ wv,
    const float* __restrict__ wo,
    u16* __restrict__ xb, u16* __restrict__ wqb, u16* __restrict__ wkb,
    u16* __restrict__ wvb, u16* __restrict__ wob)
{
    const float* srcs[5] = {x, wq, wk, wv, wo};
    u16* dsts[5] = {xb, wqb, wkb, wvb, wob};
    const int ns[5] = {4194304, 1048576, 262144, 262144, 1048576};
    int seg = blockIdx.y;
    int i = (blockIdx.x * 256 + threadIdx.x) * 4;
    if (i >= ns[seg]) return;
    float4 v = *(const float4*)(srcs[seg] + i);
    u16x4 o = {f2bf(v.x), f2bf(v.y), f2bf(v.z), f2bf(v.w)};
    *(u16x4*)(dsts[seg] + i) = o;
}

// ---------------- fused QKV MFMA GEMM, RoPE epilogue ----------------
// grid (12, 32): bx<8 -> Q (n0=bx*128), bx<10 -> K, else V. 128x128 tile, BK=32.
// Q/K: write bias+RoPE'd bf16 head-major [b][h][s][64]; V: fp32 [m][256].
__global__ __launch_bounds__(256) void gemm_qkv(
    const u16* __restrict__ Xb, const u16* __restrict__ Wqb,
    const u16* __restrict__ Wkb, const u16* __restrict__ Wvb,
    const float* __restrict__ bq, const float* __restrict__ bk,
    const float* __restrict__ bv,
    u16* __restrict__ Qp, u16* __restrict__ Kp, float* __restrict__ Vb)
{
    __shared__ u16 sA[128 * 32];
    __shared__ u16 sB[128 * 32];
    int tid = threadIdx.x, lane = tid & 63, wave = tid >> 6;
    int col = lane & 15, l4 = lane >> 4;
    int bx = blockIdx.x, m0 = blockIdx.y * 128;
    const u16* Bsrc; const float* bias; int n0, mode;
    if (bx < 8)       { mode = 0; Bsrc = Wqb; bias = bq; n0 = bx * 128; }
    else if (bx < 10) { mode = 1; Bsrc = Wkb; bias = bk; n0 = (bx - 8) * 128; }
    else              { mode = 2; Bsrc = Wvb; bias = bv; n0 = (bx - 10) * 128; }

    int i0 = tid, i1 = tid + 256;
    const u16* ga0 = Xb + (size_t)(m0 + (i0 >> 2)) * HIDDEN + (i0 & 3) * 8;
    const u16* ga1 = Xb + (size_t)(m0 + (i1 >> 2)) * HIDDEN + (i1 & 3) * 8;
    const u16* gb0 = Bsrc + (size_t)(n0 + (i0 >> 2)) * HIDDEN + (i0 & 3) * 8;
    const u16* gb1 = Bsrc + (size_t)(n0 + (i1 >> 2)) * HIDDEN + (i1 & 3) * 8;
    u16* la0 = &sA[wave * 512];
    u16* la1 = &sA[2048 + wave * 512];
    u16* lb0 = &sB[wave * 512];
    u16* lb1 = &sB[2048 + wave * 512];

    f32x4 acc[4][4];
    #pragma unroll
    for (int i = 0; i < 4; ++i)
        #pragma unroll
        for (int j = 0; j < 4; ++j) acc[i][j] = (f32x4){0.f, 0.f, 0.f, 0.f};
    int mh = (wave & 1) * 64, nh = (wave >> 1) * 64;

    for (int k0 = 0; k0 < HIDDEN; k0 += 32) {
        __syncthreads();
        async_ld16(ga0, la0); async_ld16(ga1, la1);
        async_ld16(gb0, lb0); async_ld16(gb1, lb1);
        ga0 += 32; ga1 += 32; gb0 += 32; gb1 += 32;
        __syncthreads();
        short8 af[4], bf[4];
        #pragma unroll
        for (int mi = 0; mi < 4; ++mi)
            af[mi] = *(short8*)&sA[(mh + mi * 16 + col) * 32 + l4 * 8];
        #pragma unroll
        for (int ni = 0; ni < 4; ++ni)
            bf[ni] = *(short8*)&sB[(nh + ni * 16 + col) * 32 + l4 * 8];
        #pragma unroll
        for (int mi = 0; mi < 4; ++mi)
            #pragma unroll
            for (int ni = 0; ni < 4; ++ni)
                acc[mi][ni] = __builtin_amdgcn_mfma_f32_16x16x32_bf16(af[mi], bf[ni], acc[mi][ni], 0, 0, 0);
    }

    float bcol[4];
    #pragma unroll
    for (int ni = 0; ni < 4; ++ni) bcol[ni] = bias[n0 + nh + ni * 16 + col];

    if (mode == 2) {
        #pragma unroll
        for (int mi = 0; mi < 4; ++mi)
            #pragma unroll
            for (int r = 0; r < 4; ++r) {
                int m = m0 + mh + mi * 16 + l4 * 4 + r;
                #pragma unroll
                for (int ni = 0; ni < 4; ++ni)
                    Vb[(size_t)m * 256 + n0 + nh + ni * 16 + col] = acc[mi][ni][r] + bcol[ni];
            }
    } else {
        int nheads = (mode == 0) ? NH : NKV;
        u16* outp = (mode == 0) ? Qp : Kp;
        int h = (n0 + nh) >> 6;   // 64-col wave-half = one head
        float invf[2];
        #pragma unroll
        for (int p = 0; p < 2; ++p)
            invf[p] = powf(10000.0f, -(float)(16 * p + col) * (1.0f / 32.0f));
        #pragma unroll
        for (int mi = 0; mi < 4; ++mi)
            #pragma unroll
            for (int r = 0; r < 4; ++r) {
                int m = m0 + mh + mi * 16 + l4 * 4 + r;
                int b = m >> 11, s = m & 2047;
                u16* q = outp + ((size_t)(b * nheads + h) * SEQ_ + s) * HD;
                #pragma unroll
                for (int p = 0; p < 2; ++p) {
                    float x0 = acc[mi][p][r] + bcol[p];
                    float x1 = acc[mi][p + 2][r] + bcol[p + 2];
                    float sn, cs;
                    sincosf((float)s * invf[p], &sn, &cs);
                    q[16 * p + col]      = f2bf(x0 * cs - x1 * sn);
                    q[16 * p + col + 32] = f2bf(x0 * sn + x1 * cs);
                }
            }
    }
}

// ---------------- Wo MFMA GEMM: out[M,1024] f32 = Abf[M,1024] * Wob^T ----------------
__global__ __launch_bounds__(256) void gemm_wo(
    const u16* __restrict__ Abf, const u16* __restrict__ Wob, float* __restrict__ out)
{
    __shared__ u16 sA[128 * 32];
    __shared__ u16 sB[128 * 32];
    int tid = threadIdx.x, lane = tid & 63, wave = tid >> 6;
    int col = lane & 15, l4 = lane >> 4;
    int m0 = blockIdx.y * 128, n0 = blockIdx.x * 128;
    int i0 = tid, i1 = tid + 256;
    const u16* ga0 = Abf + (size_t)(m0 + (i0 >> 2)) * HIDDEN + (i0 & 3) * 8;
    const u16* ga1 = Abf + (size_t)(m0 + (i1 >> 2)) * HIDDEN + (i1 & 3) * 8;
    const u16* gb0 = Wob + (size_t)(n0 + (i0 >> 2)) * HIDDEN + (i0 & 3) * 8;
    const u16* gb1 = Wob + (size_t)(n0 + (i1 >> 2)) * HIDDEN + (i1 & 3) * 8;
    u16* la0 = &sA[wave * 512];
    u16* la1 = &sA[2048 + wave * 512];
    u16* lb0 = &sB[wave * 512];
    u16* lb1 = &sB[2048 + wave * 512];

    f32x4 acc[4][4];
    #pragma unroll
    for (int i = 0; i < 4; ++i)
        #pragma unroll
        for (int j = 0; j < 4; ++j) acc[i][j] = (f32x4){0.f, 0.f, 0.f, 0.f};
    int mh = (wave & 1) * 64, nh = (wave >> 1) * 64;

    for (int k0 = 0; k0 < HIDDEN; k0 += 32) {
        __syncthreads();
        async_ld16(ga0, la0); async_ld16(ga1, la1);
        async_ld16(gb0, lb0); async_ld16(gb1, lb1);
        ga0 += 32; ga1 += 32; gb0 += 32; gb1 += 32;
        __syncthreads();
        short8 af[4], bf[4];
        #pragma unroll
        for (int mi = 0; mi < 4; ++mi)
            af[mi] = *(short8*)&sA[(mh + mi * 16 + col) * 32 + l4 * 8];
        #pragma unroll
        for (int ni = 0; ni < 4; ++ni)
            bf[ni] = *(short8*)&sB[(nh + ni * 16 + col) * 32 + l4 * 8];
        #pragma unroll
        for (int mi = 0; mi < 4; ++mi)
            #pragma unroll
            for (int ni = 0; ni < 4; ++ni)
                acc[mi][ni] = __builtin_amdgcn_mfma_f32_16x16x32_bf16(af[mi], bf[ni], acc[mi][ni], 0, 0, 0);
    }
    #pragma unroll
    for (int mi = 0; mi < 4; ++mi)
        #pragma unroll
        for (int r = 0; r < 4; ++r) {
            int m = m0 + mh + mi * 16 + l4 * 4 + r;
            #pragma unroll
            for (int ni = 0; ni < 4; ++ni)
                out[(size_t)m * HIDDEN + n0 + nh + ni * 16 + col] = acc[mi][ni][r];
        }
}

// ---- V transpose+cast: in [b][s][4][64] f32 -> out [b][4][64][SEQ] bf16 ----
__global__ __launch_bounds__(256) void pack_vT(const float* __restrict__ V, u16* __restrict__ out) {
    __shared__ float sT[64][65];
    int s0 = blockIdx.x * 64;
    int b = blockIdx.y >> 2, hk = blockIdx.y & 3;
    int t = threadIdx.x;
    int sl = t >> 2;
    int c0 = (t & 3) * 16;
    const float* src = V + ((size_t)(b * SEQ_ + s0 + sl) * NKV + hk) * HD + c0;
    #pragma unroll
    for (int i = 0; i < 4; ++i) {
        float4 v4 = *(const float4*)(src + i * 4);
        sT[sl][c0 + i*4 + 0] = v4.x; sT[sl][c0 + i*4 + 1] = v4.y;
        sT[sl][c0 + i*4 + 2] = v4.z; sT[sl][c0 + i*4 + 3] = v4.w;
    }
    __syncthreads();
    int d = t & 63, sc = (t >> 6) * 16;
    u16* dst = out + ((size_t)(b * NKV + hk) * HD + d) * SEQ_ + s0 + sc;
    u16 tmp[16];
    #pragma unroll
    for (int i = 0; i < 16; ++i) tmp[i] = f2bf(sT[sc + i][d]);
    *(u16x8*)dst       = *(u16x8*)&tmp[0];
    *(u16x8*)(dst + 8) = *(u16x8*)&tmp[8];
}

// ---------------- MFMA flash attention (unchanged core; bf16 output) ----------------
__global__ __launch_bounds__(256) void attn_mfma(
    const u16* __restrict__ Qp, const u16* __restrict__ Kp,
    const u16* __restrict__ Vtp, const float* __restrict__ amask,
    u16* __restrict__ Abf)
{
    __shared__ u16 sQ[64 * 72];
    __shared__ u16 sK[64 * 72];
    __shared__ u16 sVT[64 * 72];
    __shared__ u16 sP[4][16 * 72];
    __shared__ float sAm[64];
    int tid = threadIdx.x;
    int lane = tid & 63, wave = tid >> 6;
    int col = lane & 15, l4 = lane >> 4;
    int qb = blockIdx.x, bh = blockIdx.y;
    int b = bh >> 4, h = bh & 15, hk = h >> 2;
    int q0 = qb * 64;

    const u16* Qbase = Qp + ((size_t)(b * NH + h) * SEQ_ + q0) * HD;
    #pragma unroll
    for (int i = 0; i < 2; ++i) {
        int idx = tid + i * 256;
        int r_ = idx >> 3, seg = idx & 7;
        *(short8*)&sQ[r_ * 72 + seg * 8] = *(const short8*)(Qbase + r_ * HD + seg * 8);
    }
    __syncthreads();
    short8 qa0 = *(short8*)&sQ[(wave * 16 + col) * 72 + l4 * 8];
    short8 qa1 = *(short8*)&sQ[(wave * 16 + col) * 72 + 32 + l4 * 8];

    f32x4 O[4] = {{0.f,0.f,0.f,0.f},{0.f,0.f,0.f,0.f},{0.f,0.f,0.f,0.f},{0.f,0.f,0.f,0.f}};
    float mrun[4], lrun[4];
    #pragma unroll
    for (int r = 0; r < 4; ++r) { mrun[r] = -INFINITY; lrun[r] = 0.f; }

    const u16* Kbase = Kp + (size_t)(b * NKV + hk) * SEQ_ * HD;
    const u16* Vbase = Vtp + (size_t)(b * NKV + hk) * HD * SEQ_;
    int nk = min(SEQ_, q0 + 64 + WIN);
    int nkb = (nk + 63) >> 6;
    int qg = q0 + wave * 16 + l4 * 4;   // +r

    for (int kb = 0; kb < nkb; ++kb) {
        int k0 = kb * 64;
        #pragma unroll
        for (int i = 0; i < 2; ++i) {
            int idx = tid + i * 256;
            int r_ = idx >> 3, seg = idx & 7;
            *(short8*)&sK[r_ * 72 + seg * 8] =
                *(const short8*)(Kbase + (size_t)(k0 + r_) * HD + seg * 8);
            *(short8*)&sVT[r_ * 72 + seg * 8] =
                *(const short8*)(Vbase + (size_t)r_ * SEQ_ + k0 + seg * 8);
        }
        if (tid < 64) sAm[tid] = amask[b * SEQ_ + k0 + tid] * -10000.0f;
        __syncthreads();

        f32x4 S[4] = {{0.f,0.f,0.f,0.f},{0.f,0.f,0.f,0.f},{0.f,0.f,0.f,0.f},{0.f,0.f,0.f,0.f}};
        #pragma unroll
        for (int t = 0; t < 4; ++t) {
            short8 kf0 = *(short8*)&sK[(t * 16 + col) * 72 + l4 * 8];
            short8 kf1 = *(short8*)&sK[(t * 16 + col) * 72 + 32 + l4 * 8];
            S[t] = __builtin_amdgcn_mfma_f32_16x16x32_bf16(qa0, kf0, S[t], 0, 0, 0);
            S[t] = __builtin_amdgcn_mfma_f32_16x16x32_bf16(qa1, kf1, S[t], 0, 0, 0);
        }

        float am_t[4];
        #pragma unroll
        for (int t = 0; t < 4; ++t) am_t[t] = sAm[t * 16 + col];
        float sc[4][4];
        #pragma unroll
        for (int t = 0; t < 4; ++t)
            #pragma unroll
            for (int r = 0; r < 4; ++r) {
                float v = S[t][r] * 0.125f + am_t[t];
                int kg = k0 + t * 16 + col;
                sc[r][t] = (kg - (qg + r) <= WIN) ? v : -INFINITY;
            }
        float al[4];
        #pragma unroll
        for (int r = 0; r < 4; ++r) {
            float bm = fmaxf(fmaxf(sc[r][0], sc[r][1]), fmaxf(sc[r][2], sc[r][3]));
            bm = fmaxf(bm, __shfl_xor(bm, 1));
            bm = fmaxf(bm, __shfl_xor(bm, 2));
            bm = fmaxf(bm, __shfl_xor(bm, 4));
            bm = fmaxf(bm, __shfl_xor(bm, 8));
            float mnew = fmaxf(mrun[r], bm);
            al[r] = __expf(mrun[r] - mnew);
            float ps = 0.f;
            #pragma unroll
            for (int t = 0; t < 4; ++t) {
                float p = __expf(sc[r][t] - mnew);
                ps += p;
                sP[wave][(l4 * 4 + r) * 72 + t * 16 + col] = f2bf(p);
            }
            ps += __shfl_xor(ps, 1);
            ps += __shfl_xor(ps, 2);
            ps += __shfl_xor(ps, 4);
            ps += __shfl_xor(ps, 8);
            lrun[r] = lrun[r] * al[r] + ps;
            mrun[r] = mnew;
        }
        #pragma unroll
        for (int dt = 0; dt < 4; ++dt)
            #pragma unroll
            for (int r = 0; r < 4; ++r) O[dt][r] *= al[r];
        __syncthreads();

        short8 pa0 = *(short8*)&sP[wave][col * 72 + l4 * 8];
        short8 pa1 = *(short8*)&sP[wave][col * 72 + 32 + l4 * 8];
        #pragma unroll
        for (int dt = 0; dt < 4; ++dt) {
            short8 vf0 = *(short8*)&sVT[(dt * 16 + col) * 72 + l4 * 8];
            short8 vf1 = *(short8*)&sVT[(dt * 16 + col) * 72 + 32 + l4 * 8];
            O[dt] = __builtin_amdgcn_mfma_f32_16x16x32_bf16(pa0, vf0, O[dt], 0, 0, 0);
            O[dt] = __builtin_amdgcn_mfma_f32_16x16x32_bf16(pa1, vf1, O[dt], 0, 0, 0);
        }
        __syncthreads();
    }
    float inv[4];
    #pragma unroll
    for (int r = 0; r < 4; ++r) inv[r] = 1.0f / lrun[r];
    #pragma unroll
    for (int dt = 0; dt < 4; ++dt)
        #pragma unroll
        for (int r = 0; r < 4; ++r) {
            int s = q0 + wave * 16 + l4 * 4 + r;
            Abf[(size_t)(b * SEQ_ + s) * HIDDEN + h * HD + dt * 16 + col] = f2bf(O[dt][r] * inv[r]);
        }
}

extern "C" void kernel_launch(void* const* d_in, const int* in_sizes, int n_in,
                              void* d_out, int out_size, void* d_ws, size_t ws_size,
                              hipStream_t stream) {
    const float* X  = (const float*)d_in[0];
    const float* am = (const float*)d_in[1];
    const float* Wq = (const float*)d_in[2];
    const float* bq = (const float*)d_in[3];
    const float* Wk = (const float*)d_in[4];
    const float* bk = (const float*)d_in[5];
    const float* Wv = (const float*)d_in[6];
    const float* bv = (const float*)d_in[7];
    const float* Wo = (const float*)d_in[8];
    float* out = (float*)d_out;

    const int M = BS_ * SEQ_;            // 4096
    // workspace layout (29 MB total; Abf aliases Xb which dies after gemm_qkv)
    u16* Qp  = (u16*)d_ws;                         // 8 MB
    u16* Kp  = Qp + (size_t)M * HIDDEN;            // 2 MB
    u16* Vtp = Kp + (size_t)M * 256;               // 2 MB
    float* Vb = (float*)(Vtp + (size_t)M * 256);   // 4 MB
    u16* Xb  = (u16*)(Vb + (size_t)M * 256);       // 8 MB
    u16* Wqb = Xb + (size_t)M * HIDDEN;            // 2 MB
    u16* Wkb = Wqb + (size_t)HIDDEN * HIDDEN;      // 0.5 MB
    u16* Wvb = Wkb + (size_t)256 * HIDDEN;         // 0.5 MB
    u16* Wob = Wvb + (size_t)256 * HIDDEN;         // 2 MB
    u16* Abf = Xb;  // alias: Xb consumed by gemm_qkv before attn writes Abf

    dim3 blk(256);
    cast5<<<dim3(4096, 5), blk, 0, stream>>>(X, Wq, Wk, Wv, Wo, Xb, Wqb, Wkb, Wvb, Wob);
    gemm_qkv<<<dim3(12, 32), blk, 0, stream>>>(Xb, Wqb, Wkb, Wvb, bq, bk, bv, Qp, Kp, Vb);
    pack_vT<<<dim3(SEQ_ / 64, BS_ * NKV), blk, 0, stream>>>(Vb, Vtp);
    attn_mfma<<<dim3(SEQ_ / 64, BS_ * NH), blk, 0, stream>>>(Qp, Kp, Vtp, am, Abf);
    gemm_wo<<<dim3(8, 32), blk, 0, stream>>>(Abf, Wob, out);
}

// Round 4
// 233.692 us; speedup vs baseline: 4.8860x; 1.1489x over previous
//
#include <hip/hip_runtime.h>
#include <math.h>

#define HIDDEN 1024
#define NH 16
#define NKV 4
#define HD 64
#define BS_ 2
#define SEQ_ 2048
#define WIN 1534   // allowed iff k - q <= 1534

typedef unsigned short u16;
typedef short short8 __attribute__((ext_vector_type(8)));
typedef float f32x4 __attribute__((ext_vector_type(4)));
typedef u16 u16x4 __attribute__((ext_vector_type(4)));
typedef u16 u16x8 __attribute__((ext_vector_type(8)));

__device__ __forceinline__ u16 f2bf(float f) {
    unsigned u = __float_as_uint(f);
    u += 0x7fff + ((u >> 16) & 1);      // RNE
    return (u16)(u >> 16);
}

// pack two f32 -> two bf16 (truncation) in ONE v_perm_b32
__device__ __forceinline__ unsigned pk_trunc(float lo, float hi) {
    return __builtin_amdgcn_perm(__float_as_uint(hi), __float_as_uint(lo), 0x07060302u);
}

__device__ __forceinline__ void async_ld16(const u16* g, u16* l) {
    __builtin_amdgcn_global_load_lds(
        (const __attribute__((address_space(1))) unsigned int*)g,
        (__attribute__((address_space(3))) unsigned int*)l, 16, 0, 0);
}

// ---------------- cast fp32 -> bf16 for X and the 4 weights ----------------
__global__ __launch_bounds__(256) void cast5(
    const float* __restrict__ x, const float* __restrict__ wq,
    const float* __restrict__ wk, const float* __restrict__ wv,
    const float* __restrict__ wo,
    u16* __restrict__ xb, u16* __restrict__ wqb, u16* __restrict__ wkb,
    u16* __restrict__ wvb, u16* __restrict__ wob)
{
    const float* srcs[5] = {x, wq, wk, wv, wo};
    u16* dsts[5] = {xb, wqb, wkb, wvb, wob};
    const int ns[5] = {4194304, 1048576, 262144, 262144, 1048576};
    int seg = blockIdx.y;
    int i = (blockIdx.x * 256 + threadIdx.x) * 4;
    if (i >= ns[seg]) return;
    float4 v = *(const float4*)(srcs[seg] + i);
    u16x4 o = {f2bf(v.x), f2bf(v.y), f2bf(v.z), f2bf(v.w)};
    *(u16x4*)(dsts[seg] + i) = o;
}

// ---------------- fused QKV MFMA GEMM ----------------
// grid (12, 32): bx<8 -> Q, bx<10 -> K, else V. 128x128 tile, BK=32.
// Q/K: bias+RoPE'd bf16 head-major [b][h][s][64]; V: bias + bf16 V^T [b][hk][d][SEQ].
__global__ __launch_bounds__(256) void gemm_qkv(
    const u16* __restrict__ Xb, const u16* __restrict__ Wqb,
    const u16* __restrict__ Wkb, const u16* __restrict__ Wvb,
    const float* __restrict__ bq, const float* __restrict__ bk,
    const float* __restrict__ bv,
    u16* __restrict__ Qp, u16* __restrict__ Kp, u16* __restrict__ Vtp)
{
    __shared__ u16 sA[128 * 32];
    __shared__ u16 sB[128 * 32];
    int tid = threadIdx.x, lane = tid & 63, wave = tid >> 6;
    int col = lane & 15, l4 = lane >> 4;
    int bx = blockIdx.x, m0 = blockIdx.y * 128;
    const u16* Bsrc; const float* bias; int n0, mode;
    if (bx < 8)       { mode = 0; Bsrc = Wqb; bias = bq; n0 = bx * 128; }
    else if (bx < 10) { mode = 1; Bsrc = Wkb; bias = bk; n0 = (bx - 8) * 128; }
    else              { mode = 2; Bsrc = Wvb; bias = bv; n0 = (bx - 10) * 128; }

    int i0 = tid, i1 = tid + 256;
    const u16* ga0 = Xb + (size_t)(m0 + (i0 >> 2)) * HIDDEN + (i0 & 3) * 8;
    const u16* ga1 = Xb + (size_t)(m0 + (i1 >> 2)) * HIDDEN + (i1 & 3) * 8;
    const u16* gb0 = Bsrc + (size_t)(n0 + (i0 >> 2)) * HIDDEN + (i0 & 3) * 8;
    const u16* gb1 = Bsrc + (size_t)(n0 + (i1 >> 2)) * HIDDEN + (i1 & 3) * 8;
    u16* la0 = &sA[wave * 512];
    u16* la1 = &sA[2048 + wave * 512];
    u16* lb0 = &sB[wave * 512];
    u16* lb1 = &sB[2048 + wave * 512];

    f32x4 acc[4][4];
    #pragma unroll
    for (int i = 0; i < 4; ++i)
        #pragma unroll
        for (int j = 0; j < 4; ++j) acc[i][j] = (f32x4){0.f, 0.f, 0.f, 0.f};
    int mh = (wave & 1) * 64, nh = (wave >> 1) * 64;

    for (int k0 = 0; k0 < HIDDEN; k0 += 32) {
        __syncthreads();
        async_ld16(ga0, la0); async_ld16(ga1, la1);
        async_ld16(gb0, lb0); async_ld16(gb1, lb1);
        ga0 += 32; ga1 += 32; gb0 += 32; gb1 += 32;
        __syncthreads();
        short8 af[4], bf[4];
        #pragma unroll
        for (int mi = 0; mi < 4; ++mi)
            af[mi] = *(short8*)&sA[(mh + mi * 16 + col) * 32 + l4 * 8];
        #pragma unroll
        for (int ni = 0; ni < 4; ++ni)
            bf[ni] = *(short8*)&sB[(nh + ni * 16 + col) * 32 + l4 * 8];
        #pragma unroll
        for (int mi = 0; mi < 4; ++mi)
            #pragma unroll
            for (int ni = 0; ni < 4; ++ni)
                acc[mi][ni] = __builtin_amdgcn_mfma_f32_16x16x32_bf16(af[mi], bf[ni], acc[mi][ni], 0, 0, 0);
    }

    float bcol[4];
    #pragma unroll
    for (int ni = 0; ni < 4; ++ni) bcol[ni] = bias[n0 + nh + ni * 16 + col];

    if (mode == 2) {
        // V^T bf16: [b][hk][d][SEQ]; s contiguous over r -> b64 stores
        #pragma unroll
        for (int mi = 0; mi < 4; ++mi) {
            int m = m0 + mh + mi * 16 + l4 * 4;
            int b = m >> 11, s = m & 2047;
            #pragma unroll
            for (int ni = 0; ni < 4; ++ni) {
                int dg = n0 + nh + ni * 16 + col;
                u16x4 pk = {f2bf(acc[mi][ni][0] + bcol[ni]), f2bf(acc[mi][ni][1] + bcol[ni]),
                            f2bf(acc[mi][ni][2] + bcol[ni]), f2bf(acc[mi][ni][3] + bcol[ni])};
                *(u16x4*)&Vtp[((size_t)(b * NKV + (dg >> 6)) * HD + (dg & 63)) * SEQ_ + s] = pk;
            }
        }
    } else {
        int nheads = (mode == 0) ? NH : NKV;
        u16* outp = (mode == 0) ? Qp : Kp;
        int h = (n0 + nh) >> 6;   // 64-col wave-half = one head
        float invf[2];
        #pragma unroll
        for (int p = 0; p < 2; ++p)
            invf[p] = powf(10000.0f, -(float)(16 * p + col) * (1.0f / 32.0f));
        #pragma unroll
        for (int mi = 0; mi < 4; ++mi)
            #pragma unroll
            for (int r = 0; r < 4; ++r) {
                int m = m0 + mh + mi * 16 + l4 * 4 + r;
                int b = m >> 11, s = m & 2047;
                u16* q = outp + ((size_t)(b * nheads + h) * SEQ_ + s) * HD;
                #pragma unroll
                for (int p = 0; p < 2; ++p) {
                    float x0 = acc[mi][p][r] + bcol[p];
                    float x1 = acc[mi][p + 2][r] + bcol[p + 2];
                    float sn, cs;
                    sincosf((float)s * invf[p], &sn, &cs);
                    q[16 * p + col]      = f2bf(x0 * cs - x1 * sn);
                    q[16 * p + col + 32] = f2bf(x0 * sn + x1 * cs);
                }
            }
    }
}

// ---------------- Wo MFMA GEMM: out[M,1024] f32 = Abf[M,1024] * Wob^T ----------------
__global__ __launch_bounds__(256) void gemm_wo(
    const u16* __restrict__ Abf, const u16* __restrict__ Wob, float* __restrict__ out)
{
    __shared__ u16 sA[128 * 32];
    __shared__ u16 sB[128 * 32];
    int tid = threadIdx.x, lane = tid & 63, wave = tid >> 6;
    int col = lane & 15, l4 = lane >> 4;
    int m0 = blockIdx.y * 128, n0 = blockIdx.x * 128;
    int i0 = tid, i1 = tid + 256;
    const u16* ga0 = Abf + (size_t)(m0 + (i0 >> 2)) * HIDDEN + (i0 & 3) * 8;
    const u16* ga1 = Abf + (size_t)(m0 + (i1 >> 2)) * HIDDEN + (i1 & 3) * 8;
    const u16* gb0 = Wob + (size_t)(n0 + (i0 >> 2)) * HIDDEN + (i0 & 3) * 8;
    const u16* gb1 = Wob + (size_t)(n0 + (i1 >> 2)) * HIDDEN + (i1 & 3) * 8;
    u16* la0 = &sA[wave * 512];
    u16* la1 = &sA[2048 + wave * 512];
    u16* lb0 = &sB[wave * 512];
    u16* lb1 = &sB[2048 + wave * 512];

    f32x4 acc[4][4];
    #pragma unroll
    for (int i = 0; i < 4; ++i)
        #pragma unroll
        for (int j = 0; j < 4; ++j) acc[i][j] = (f32x4){0.f, 0.f, 0.f, 0.f};
    int mh = (wave & 1) * 64, nh = (wave >> 1) * 64;

    for (int k0 = 0; k0 < HIDDEN; k0 += 32) {
        __syncthreads();
        async_ld16(ga0, la0); async_ld16(ga1, la1);
        async_ld16(gb0, lb0); async_ld16(gb1, lb1);
        ga0 += 32; ga1 += 32; gb0 += 32; gb1 += 32;
        __syncthreads();
        short8 af[4], bf[4];
        #pragma unroll
        for (int mi = 0; mi < 4; ++mi)
            af[mi] = *(short8*)&sA[(mh + mi * 16 + col) * 32 + l4 * 8];
        #pragma unroll
        for (int ni = 0; ni < 4; ++ni)
            bf[ni] = *(short8*)&sB[(nh + ni * 16 + col) * 32 + l4 * 8];
        #pragma unroll
        for (int mi = 0; mi < 4; ++mi)
            #pragma unroll
            for (int ni = 0; ni < 4; ++ni)
                acc[mi][ni] = __builtin_amdgcn_mfma_f32_16x16x32_bf16(af[mi], bf[ni], acc[mi][ni], 0, 0, 0);
    }
    #pragma unroll
    for (int mi = 0; mi < 4; ++mi)
        #pragma unroll
        for (int r = 0; r < 4; ++r) {
            int m = m0 + mh + mi * 16 + l4 * 4 + r;
            #pragma unroll
            for (int ni = 0; ni < 4; ++ni)
                out[(size_t)m * HIDDEN + n0 + nh + ni * 16 + col] = acc[mi][ni][r];
        }
}

// ---------------- MFMA flash attention, transposed-S softmax ----------------
// S^T = mfma(K-frag, Q-frag): lane owns q=col, keys = 16t + l4*4 + r (contiguous).
__global__ __launch_bounds__(256) void attn_mfma(
    const u16* __restrict__ Qp, const u16* __restrict__ Kp,
    const u16* __restrict__ Vtp, const float* __restrict__ amask,
    u16* __restrict__ Abf)
{
    __shared__ u16 sQ[64 * 72];
    __shared__ u16 sK[64 * 72];
    __shared__ u16 sVT[64 * 72];
    __shared__ u16 sP[4][16 * 72];
    __shared__ float sAm[64];
    int tid = threadIdx.x;
    int lane = tid & 63, wave = tid >> 6;
    int col = lane & 15, l4 = lane >> 4;
    int qb = blockIdx.x, bh = blockIdx.y;
    int b = bh >> 4, h = bh & 15, hk = h >> 2;
    int q0 = qb * 64;

    const u16* Qbase = Qp + ((size_t)(b * NH + h) * SEQ_ + q0) * HD;
    #pragma unroll
    for (int i = 0; i < 2; ++i) {
        int idx = tid + i * 256;
        int r_ = idx >> 3, seg = idx & 7;
        *(short8*)&sQ[r_ * 72 + seg * 8] = *(const short8*)(Qbase + r_ * HD + seg * 8);
    }
    __syncthreads();
    short8 qa0 = *(short8*)&sQ[(wave * 16 + col) * 72 + l4 * 8];
    short8 qa1 = *(short8*)&sQ[(wave * 16 + col) * 72 + 32 + l4 * 8];

    f32x4 O[4] = {{0.f,0.f,0.f,0.f},{0.f,0.f,0.f,0.f},{0.f,0.f,0.f,0.f},{0.f,0.f,0.f,0.f}};
    float mrun = -INFINITY, lrun = 0.f;   // owner: q = q0 + wave*16 + col
    int qcol = q0 + wave * 16 + col;

    const u16* Kbase = Kp + (size_t)(b * NKV + hk) * SEQ_ * HD;
    const u16* Vbase = Vtp + (size_t)(b * NKV + hk) * HD * SEQ_;
    int nk = min(SEQ_, q0 + 64 + WIN);
    int nkb = (nk + 63) >> 6;

    for (int kb = 0; kb < nkb; ++kb) {
        int k0 = kb * 64;
        #pragma unroll
        for (int i = 0; i < 2; ++i) {
            int idx = tid + i * 256;
            int r_ = idx >> 3, seg = idx & 7;
            *(short8*)&sK[r_ * 72 + seg * 8] =
                *(const short8*)(Kbase + (size_t)(k0 + r_) * HD + seg * 8);
            *(short8*)&sVT[r_ * 72 + seg * 8] =
                *(const short8*)(Vbase + (size_t)r_ * SEQ_ + k0 + seg * 8);
        }
        if (tid < 64) sAm[tid] = amask[b * SEQ_ + k0 + tid] * -10000.0f;
        __syncthreads();

        bool dead = k0 > q0 + wave * 16 + 15 + WIN;   // wave-uniform
        if (!dead) {
            f32x4 St[4] = {{0.f,0.f,0.f,0.f},{0.f,0.f,0.f,0.f},{0.f,0.f,0.f,0.f},{0.f,0.f,0.f,0.f}};
            #pragma unroll
            for (int t = 0; t < 4; ++t) {
                short8 kf0 = *(short8*)&sK[(t * 16 + col) * 72 + l4 * 8];
                short8 kf1 = *(short8*)&sK[(t * 16 + col) * 72 + 32 + l4 * 8];
                St[t] = __builtin_amdgcn_mfma_f32_16x16x32_bf16(kf0, qa0, St[t], 0, 0, 0);
                St[t] = __builtin_amdgcn_mfma_f32_16x16x32_bf16(kf1, qa1, St[t], 0, 0, 0);
            }
            bool full = (k0 + 63) <= (q0 + wave * 16 + WIN);   // wave-uniform
            float p[4][4];
            float mx = -INFINITY;
            #pragma unroll
            for (int t = 0; t < 4; ++t) {
                float4 amv = *(float4*)&sAm[16 * t + l4 * 4];
                float amr[4] = {amv.x, amv.y, amv.z, amv.w};
                #pragma unroll
                for (int r = 0; r < 4; ++r) {
                    float s = St[t][r] * 0.125f + amr[r];
                    if (!full) {
                        int kg = k0 + 16 * t + l4 * 4 + r;
                        s = (kg - qcol <= WIN) ? s : -INFINITY;
                    }
                    p[t][r] = s;
                    mx = fmaxf(mx, s);
                }
            }
            mx = fmaxf(mx, __shfl_xor(mx, 16));
            mx = fmaxf(mx, __shfl_xor(mx, 32));
            float mnew = fmaxf(mrun, mx);
            float alpha = __expf(mrun - mnew);
            float ps = 0.f;
            #pragma unroll
            for (int t = 0; t < 4; ++t)
                #pragma unroll
                for (int r = 0; r < 4; ++r) {
                    float e = __expf(p[t][r] - mnew);
                    p[t][r] = e;
                    ps += e;
                }
            ps += __shfl_xor(ps, 16);
            ps += __shfl_xor(ps, 32);
            lrun = lrun * alpha + ps;
            mrun = mnew;
            // packed P write: 4 keys contiguous -> one b64 per tile
            #pragma unroll
            for (int t = 0; t < 4; ++t) {
                uint2 w;
                w.x = pk_trunc(p[t][0], p[t][1]);
                w.y = pk_trunc(p[t][2], p[t][3]);
                *(uint2*)&sP[wave][col * 72 + 16 * t + l4 * 4] = w;
            }
            // rescale O rows (q = l4*4 + r) by alpha from owner lane
            #pragma unroll
            for (int r = 0; r < 4; ++r) {
                float ar = __shfl(alpha, l4 * 4 + r);
                #pragma unroll
                for (int dt = 0; dt < 4; ++dt) O[dt][r] *= ar;
            }
            // PV: sP is wave-private; in-wave lgkmcnt ordering suffices (no barrier)
            short8 pa0 = *(short8*)&sP[wave][col * 72 + l4 * 8];
            short8 pa1 = *(short8*)&sP[wave][col * 72 + 32 + l4 * 8];
            #pragma unroll
            for (int dt = 0; dt < 4; ++dt) {
                short8 vf0 = *(short8*)&sVT[(dt * 16 + col) * 72 + l4 * 8];
                short8 vf1 = *(short8*)&sVT[(dt * 16 + col) * 72 + 32 + l4 * 8];
                O[dt] = __builtin_amdgcn_mfma_f32_16x16x32_bf16(pa0, vf0, O[dt], 0, 0, 0);
                O[dt] = __builtin_amdgcn_mfma_f32_16x16x32_bf16(pa1, vf1, O[dt], 0, 0, 0);
            }
        }
        __syncthreads();   // protect sK/sVT/sAm before restage
    }
    float linv = 1.0f / lrun;   // owner lanes
    float lr[4];
    #pragma unroll
    for (int r = 0; r < 4; ++r) lr[r] = __shfl(linv, l4 * 4 + r);
    #pragma unroll
    for (int dt = 0; dt < 4; ++dt)
        #pragma unroll
        for (int r = 0; r < 4; ++r) {
            int s = q0 + wave * 16 + l4 * 4 + r;
            Abf[(size_t)(b * SEQ_ + s) * HIDDEN + h * HD + dt * 16 + col] = f2bf(O[dt][r] * lr[r]);
        }
}

extern "C" void kernel_launch(void* const* d_in, const int* in_sizes, int n_in,
                              void* d_out, int out_size, void* d_ws, size_t ws_size,
                              hipStream_t stream) {
    const float* X  = (const float*)d_in[0];
    const float* am = (const float*)d_in[1];
    const float* Wq = (const float*)d_in[2];
    const float* bq = (const float*)d_in[3];
    const float* Wk = (const float*)d_in[4];
    const float* bk = (const float*)d_in[5];
    const float* Wv = (const float*)d_in[6];
    const float* bv = (const float*)d_in[7];
    const float* Wo = (const float*)d_in[8];
    float* out = (float*)d_out;

    const int M = BS_ * SEQ_;            // 4096
    u16* Qp  = (u16*)d_ws;                         // 8 MB
    u16* Kp  = Qp + (size_t)M * HIDDEN;            // 2 MB
    u16* Vtp = Kp + (size_t)M * 256;               // 2 MB
    u16* Xb  = Vtp + (size_t)M * 256;              // 8 MB
    u16* Wqb = Xb + (size_t)M * HIDDEN;            // 2 MB
    u16* Wkb = Wqb + (size_t)HIDDEN * HIDDEN;      // 0.5 MB
    u16* Wvb = Wkb + (size_t)256 * HIDDEN;         // 0.5 MB
    u16* Wob = Wvb + (size_t)256 * HIDDEN;         // 2 MB
    u16* Abf = Xb;  // alias: Xb consumed by gemm_qkv before attn writes Abf

    dim3 blk(256);
    cast5<<<dim3(4096, 5), blk, 0, stream>>>(X, Wq, Wk, Wv, Wo, Xb, Wqb, Wkb, Wvb, Wob);
    gemm_qkv<<<dim3(12, 32), blk, 0, stream>>>(Xb, Wqb, Wkb, Wvb, bq, bk, bv, Qp, Kp, Vtp);
    attn_mfma<<<dim3(SEQ_ / 64, BS_ * NH), blk, 0, stream>>>(Qp, Kp, Vtp, am, Abf);
    gemm_wo<<<dim3(8, 32), blk, 0, stream>>>(Abf, Wob, out);
}

// Round 5
// 218.025 us; speedup vs baseline: 5.2370x; 1.0719x over previous
//
#include <hip/hip_runtime.h>
#include <math.h>

#define HIDDEN 1024
#define NH 16
#define NKV 4
#define HD 64
#define BS_ 2
#define SEQ_ 2048
#define WIN 1534   // allowed iff k - q <= 1534

typedef unsigned short u16;
typedef short short8 __attribute__((ext_vector_type(8)));
typedef float f32x4 __attribute__((ext_vector_type(4)));
typedef u16 u16x4 __attribute__((ext_vector_type(4)));

__device__ __forceinline__ u16 f2bf(float f) {
    unsigned u = __float_as_uint(f);
    u += 0x7fff + ((u >> 16) & 1);      // RNE
    return (u16)(u >> 16);
}

// pack two f32 -> two bf16 (truncation) in ONE v_perm_b32
__device__ __forceinline__ unsigned pk_trunc(float lo, float hi) {
    return __builtin_amdgcn_perm(__float_as_uint(hi), __float_as_uint(lo), 0x07060302u);
}

__device__ __forceinline__ void async_ld16(const u16* g, u16* l) {
    __builtin_amdgcn_global_load_lds(
        (const __attribute__((address_space(1))) unsigned int*)g,
        (__attribute__((address_space(3))) unsigned int*)l, 16, 0, 0);
}

// ---------------- cast fp32 -> bf16 (X + 4 weights) and pre-scale amask ----------------
__global__ __launch_bounds__(256) void cast6(
    const float* __restrict__ x, const float* __restrict__ wq,
    const float* __restrict__ wk, const float* __restrict__ wv,
    const float* __restrict__ wo, const float* __restrict__ amask,
    u16* __restrict__ xb, u16* __restrict__ wqb, u16* __restrict__ wkb,
    u16* __restrict__ wvb, u16* __restrict__ wob, float* __restrict__ ams)
{
    int seg = blockIdx.y;
    int i = (blockIdx.x * 256 + threadIdx.x) * 4;
    if (seg == 5) {
        if (i >= BS_ * SEQ_) return;
        float4 v = *(const float4*)(amask + i);
        float4 o = make_float4(v.x * -10000.f, v.y * -10000.f, v.z * -10000.f, v.w * -10000.f);
        *(float4*)(ams + i) = o;
        return;
    }
    const float* srcs[5] = {x, wq, wk, wv, wo};
    u16* dsts[5] = {xb, wqb, wkb, wvb, wob};
    const int ns[5] = {4194304, 1048576, 262144, 262144, 1048576};
    if (i >= ns[seg]) return;
    float4 v = *(const float4*)(srcs[seg] + i);
    u16x4 o = {f2bf(v.x), f2bf(v.y), f2bf(v.z), f2bf(v.w)};
    *(u16x4*)(dsts[seg] + i) = o;
}

// ---------------- fused QKV MFMA GEMM ----------------
// grid (12, 32): bx<8 -> Q, bx<10 -> K, else V. 128x128 tile, BK=32.
// Q: bias+RoPE, pre-scaled by 1/8, bf16 head-major [b][h][s][64]
// K: bias+RoPE bf16 head-major; V: bias + bf16 V^T [b][hk][d][SEQ].
__global__ __launch_bounds__(256) void gemm_qkv(
    const u16* __restrict__ Xb, const u16* __restrict__ Wqb,
    const u16* __restrict__ Wkb, const u16* __restrict__ Wvb,
    const float* __restrict__ bq, const float* __restrict__ bk,
    const float* __restrict__ bv,
    u16* __restrict__ Qp, u16* __restrict__ Kp, u16* __restrict__ Vtp)
{
    __shared__ u16 sA[128 * 32];
    __shared__ u16 sB[128 * 32];
    int tid = threadIdx.x, lane = tid & 63, wave = tid >> 6;
    int col = lane & 15, l4 = lane >> 4;
    int bx = blockIdx.x, m0 = blockIdx.y * 128;
    const u16* Bsrc; const float* bias; int n0, mode;
    if (bx < 8)       { mode = 0; Bsrc = Wqb; bias = bq; n0 = bx * 128; }
    else if (bx < 10) { mode = 1; Bsrc = Wkb; bias = bk; n0 = (bx - 8) * 128; }
    else              { mode = 2; Bsrc = Wvb; bias = bv; n0 = (bx - 10) * 128; }

    int i0 = tid, i1 = tid + 256;
    const u16* ga0 = Xb + (size_t)(m0 + (i0 >> 2)) * HIDDEN + (i0 & 3) * 8;
    const u16* ga1 = Xb + (size_t)(m0 + (i1 >> 2)) * HIDDEN + (i1 & 3) * 8;
    const u16* gb0 = Bsrc + (size_t)(n0 + (i0 >> 2)) * HIDDEN + (i0 & 3) * 8;
    const u16* gb1 = Bsrc + (size_t)(n0 + (i1 >> 2)) * HIDDEN + (i1 & 3) * 8;
    u16* la0 = &sA[wave * 512];
    u16* la1 = &sA[2048 + wave * 512];
    u16* lb0 = &sB[wave * 512];
    u16* lb1 = &sB[2048 + wave * 512];

    f32x4 acc[4][4];
    #pragma unroll
    for (int i = 0; i < 4; ++i)
        #pragma unroll
        for (int j = 0; j < 4; ++j) acc[i][j] = (f32x4){0.f, 0.f, 0.f, 0.f};
    int mh = (wave & 1) * 64, nh = (wave >> 1) * 64;

    for (int k0 = 0; k0 < HIDDEN; k0 += 32) {
        __syncthreads();
        async_ld16(ga0, la0); async_ld16(ga1, la1);
        async_ld16(gb0, lb0); async_ld16(gb1, lb1);
        ga0 += 32; ga1 += 32; gb0 += 32; gb1 += 32;
        __syncthreads();
        short8 af[4], bf[4];
        #pragma unroll
        for (int mi = 0; mi < 4; ++mi)
            af[mi] = *(short8*)&sA[(mh + mi * 16 + col) * 32 + l4 * 8];
        #pragma unroll
        for (int ni = 0; ni < 4; ++ni)
            bf[ni] = *(short8*)&sB[(nh + ni * 16 + col) * 32 + l4 * 8];
        #pragma unroll
        for (int mi = 0; mi < 4; ++mi)
            #pragma unroll
            for (int ni = 0; ni < 4; ++ni)
                acc[mi][ni] = __builtin_amdgcn_mfma_f32_16x16x32_bf16(af[mi], bf[ni], acc[mi][ni], 0, 0, 0);
    }

    float bcol[4];
    #pragma unroll
    for (int ni = 0; ni < 4; ++ni) bcol[ni] = bias[n0 + nh + ni * 16 + col];

    if (mode == 2) {
        // V^T bf16: [b][hk][d][SEQ]; s contiguous over r -> b64 stores
        #pragma unroll
        for (int mi = 0; mi < 4; ++mi) {
            int m = m0 + mh + mi * 16 + l4 * 4;
            int b = m >> 11, s = m & 2047;
            #pragma unroll
            for (int ni = 0; ni < 4; ++ni) {
                int dg = n0 + nh + ni * 16 + col;
                u16x4 pk = {f2bf(acc[mi][ni][0] + bcol[ni]), f2bf(acc[mi][ni][1] + bcol[ni]),
                            f2bf(acc[mi][ni][2] + bcol[ni]), f2bf(acc[mi][ni][3] + bcol[ni])};
                *(u16x4*)&Vtp[((size_t)(b * NKV + (dg >> 6)) * HD + (dg & 63)) * SEQ_ + s] = pk;
            }
        }
    } else {
        int nheads = (mode == 0) ? NH : NKV;
        u16* outp = (mode == 0) ? Qp : Kp;
        float osc = (mode == 0) ? 0.125f : 1.0f;   // fold 1/sqrt(64) into Q
        int h = (n0 + nh) >> 6;   // 64-col wave-half = one head
        float invf[2];
        #pragma unroll
        for (int p = 0; p < 2; ++p)
            invf[p] = powf(10000.0f, -(float)(16 * p + col) * (1.0f / 32.0f));
        #pragma unroll
        for (int mi = 0; mi < 4; ++mi)
            #pragma unroll
            for (int r = 0; r < 4; ++r) {
                int m = m0 + mh + mi * 16 + l4 * 4 + r;
                int b = m >> 11, s = m & 2047;
                u16* q = outp + ((size_t)(b * nheads + h) * SEQ_ + s) * HD;
                #pragma unroll
                for (int p = 0; p < 2; ++p) {
                    float x0 = acc[mi][p][r] + bcol[p];
                    float x1 = acc[mi][p + 2][r] + bcol[p + 2];
                    float sn, cs;
                    __sincosf((float)s * invf[p], &sn, &cs);
                    q[16 * p + col]      = f2bf((x0 * cs - x1 * sn) * osc);
                    q[16 * p + col + 32] = f2bf((x0 * sn + x1 * cs) * osc);
                }
            }
    }
}

// ---------------- Wo MFMA GEMM: out[M,1024] f32 = Abf[M,1024] * Wob^T ----------------
__global__ __launch_bounds__(256) void gemm_wo(
    const u16* __restrict__ Abf, const u16* __restrict__ Wob, float* __restrict__ out)
{
    __shared__ u16 sA[128 * 32];
    __shared__ u16 sB[128 * 32];
    int tid = threadIdx.x, lane = tid & 63, wave = tid >> 6;
    int col = lane & 15, l4 = lane >> 4;
    int m0 = blockIdx.y * 128, n0 = blockIdx.x * 128;
    int i0 = tid, i1 = tid + 256;
    const u16* ga0 = Abf + (size_t)(m0 + (i0 >> 2)) * HIDDEN + (i0 & 3) * 8;
    const u16* ga1 = Abf + (size_t)(m0 + (i1 >> 2)) * HIDDEN + (i1 & 3) * 8;
    const u16* gb0 = Wob + (size_t)(n0 + (i0 >> 2)) * HIDDEN + (i0 & 3) * 8;
    const u16* gb1 = Wob + (size_t)(n0 + (i1 >> 2)) * HIDDEN + (i1 & 3) * 8;
    u16* la0 = &sA[wave * 512];
    u16* la1 = &sA[2048 + wave * 512];
    u16* lb0 = &sB[wave * 512];
    u16* lb1 = &sB[2048 + wave * 512];

    f32x4 acc[4][4];
    #pragma unroll
    for (int i = 0; i < 4; ++i)
        #pragma unroll
        for (int j = 0; j < 4; ++j) acc[i][j] = (f32x4){0.f, 0.f, 0.f, 0.f};
    int mh = (wave & 1) * 64, nh = (wave >> 1) * 64;

    for (int k0 = 0; k0 < HIDDEN; k0 += 32) {
        __syncthreads();
        async_ld16(ga0, la0); async_ld16(ga1, la1);
        async_ld16(gb0, lb0); async_ld16(gb1, lb1);
        ga0 += 32; ga1 += 32; gb0 += 32; gb1 += 32;
        __syncthreads();
        short8 af[4], bf[4];
        #pragma unroll
        for (int mi = 0; mi < 4; ++mi)
            af[mi] = *(short8*)&sA[(mh + mi * 16 + col) * 32 + l4 * 8];
        #pragma unroll
        for (int ni = 0; ni < 4; ++ni)
            bf[ni] = *(short8*)&sB[(nh + ni * 16 + col) * 32 + l4 * 8];
        #pragma unroll
        for (int mi = 0; mi < 4; ++mi)
            #pragma unroll
            for (int ni = 0; ni < 4; ++ni)
                acc[mi][ni] = __builtin_amdgcn_mfma_f32_16x16x32_bf16(af[mi], bf[ni], acc[mi][ni], 0, 0, 0);
    }
    #pragma unroll
    for (int mi = 0; mi < 4; ++mi)
        #pragma unroll
        for (int r = 0; r < 4; ++r) {
            int m = m0 + mh + mi * 16 + l4 * 4 + r;
            #pragma unroll
            for (int ni = 0; ni < 4; ++ni)
                out[(size_t)m * HIDDEN + n0 + nh + ni * 16 + col] = acc[mi][ni][r];
        }
}

// ---------------- MFMA flash attention v3 ----------------
// 128 q/WG, 32 q/wave (2 q-tiles). Transposed-S; fixed (no-max) softmax.
// K/V^T staged by global_load_lds into XOR-swizzled chunks; Q frags direct global.
__global__ __launch_bounds__(256) void attn_mfma(
    const u16* __restrict__ Qp, const u16* __restrict__ Kp,
    const u16* __restrict__ Vtp, const float* __restrict__ ams,
    u16* __restrict__ Abf)
{
    __shared__ u16 sK[4096];         // 64 keys x 64 d, chunk(row,c) holds logical c^(row&7)
    __shared__ u16 sVT[4096];        // 64 d x 64 keys, same swizzle
    __shared__ u16 sP[4][2][16 * 72];
    int tid = threadIdx.x;
    int lane = tid & 63, wave = tid >> 6;
    int col = lane & 15, l4 = lane >> 4;
    int qb = blockIdx.x, bh = blockIdx.y;
    int b = bh >> 4, h = bh & 15, hk = h >> 2;
    int q0 = qb * 128;

    // Q fragments direct from global (B-operand: lane(col,l4) = Q[q=col][d=l4*8+j])
    const u16* Qb_ = Qp + ((size_t)(b * NH + h) * SEQ_ + q0) * HD;
    short8 qa[2][2];
    #pragma unroll
    for (int qt = 0; qt < 2; ++qt) {
        const u16* qp = Qb_ + (size_t)(qt * 64 + wave * 16 + col) * HD;
        qa[qt][0] = *(const short8*)(qp + l4 * 8);
        qa[qt][1] = *(const short8*)(qp + 32 + l4 * 8);
    }

    // staging: dest chunk ci = j*256 + tid; row = ci>>3, c = tid&7, src chunk = c^(row&7)
    int srow = tid >> 3;                                   // rows 0..31 (+32 for j=1)
    int swc = ((tid & 7) ^ (srow & 7)) * 8;                // u16 offset in row
    const u16* Kbase = Kp + (size_t)(b * NKV + hk) * SEQ_ * HD;
    const u16* Vbase = Vtp + (size_t)(b * NKV + hk) * HD * SEQ_;
    const u16* pK0 = Kbase + (size_t)srow * HD + swc;
    const u16* pK1 = Kbase + (size_t)(32 + srow) * HD + swc;
    const u16* pV0 = Vbase + (size_t)srow * SEQ_ + swc;
    const u16* pV1 = Vbase + (size_t)(32 + srow) * SEQ_ + swc;
    u16* dK0 = &sK[wave * 512];
    u16* dK1 = &sK[2048 + wave * 512];
    u16* dV0 = &sVT[wave * 512];
    u16* dV1 = &sVT[2048 + wave * 512];

    int sl0 = (l4 ^ (col & 7)) * 8;      // swizzled chunk offset for frag half 0
    int sl1 = sl0 ^ 32;                  // half 1 (chunk l4+4)

    f32x4 O[2][4];
    #pragma unroll
    for (int qt = 0; qt < 2; ++qt)
        #pragma unroll
        for (int dt = 0; dt < 4; ++dt) O[qt][dt] = (f32x4){0.f, 0.f, 0.f, 0.f};
    float lsum[2] = {0.f, 0.f};

    const float* amp = ams + b * SEQ_;
    int nk = min(SEQ_, q0 + 128 + WIN);
    int nkb = (nk + 63) >> 6;

    for (int kb = 0; kb < nkb; ++kb) {
        int k0 = kb * 64;
        __syncthreads();   // prior tile's reads complete
        async_ld16(pK0 + (size_t)k0 * HD, dK0);
        async_ld16(pK1 + (size_t)k0 * HD, dK1);
        async_ld16(pV0 + k0, dV0);
        async_ld16(pV1 + k0, dV1);
        float4 amv[4];
        #pragma unroll
        for (int t = 0; t < 4; ++t)
            amv[t] = *(const float4*)(amp + k0 + 16 * t + l4 * 4);
        __syncthreads();   // DMA landed

        // K fragments (shared by both q-tiles)
        short8 kf[4][2];
        #pragma unroll
        for (int t = 0; t < 4; ++t) {
            kf[t][0] = *(short8*)&sK[(t * 16 + col) * 64 + sl0];
            kf[t][1] = *(short8*)&sK[(t * 16 + col) * 64 + sl1];
        }
        bool dead0 = k0 > q0 + wave * 16 + 15 + WIN;        // q-tile 0 (lower q) dies first
        f32x4 St[2][4];
        #pragma unroll
        for (int qt = 0; qt < 2; ++qt)
            #pragma unroll
            for (int t = 0; t < 4; ++t) St[qt][t] = (f32x4){0.f, 0.f, 0.f, 0.f};
        #pragma unroll
        for (int t = 0; t < 4; ++t) {
            if (!dead0) {
                St[0][t] = __builtin_amdgcn_mfma_f32_16x16x32_bf16(kf[t][0], qa[0][0], St[0][t], 0, 0, 0);
                St[0][t] = __builtin_amdgcn_mfma_f32_16x16x32_bf16(kf[t][1], qa[0][1], St[0][t], 0, 0, 0);
            }
            St[1][t] = __builtin_amdgcn_mfma_f32_16x16x32_bf16(kf[t][0], qa[1][0], St[1][t], 0, 0, 0);
            St[1][t] = __builtin_amdgcn_mfma_f32_16x16x32_bf16(kf[t][1], qa[1][1], St[1][t], 0, 0, 0);
        }
        // V fragments (kf now dead; shared by both q-tiles)
        short8 vf[4][2];
        #pragma unroll
        for (int dt = 0; dt < 4; ++dt) {
            vf[dt][0] = *(short8*)&sVT[(dt * 16 + col) * 64 + sl0];
            vf[dt][1] = *(short8*)&sVT[(dt * 16 + col) * 64 + sl1];
        }

        #pragma unroll
        for (int qt = 0; qt < 2; ++qt) {
            int base_q = q0 + qt * 64 + wave * 16;
            if (qt == 0 && dead0) continue;
            bool full = (k0 + 63) <= (base_q + WIN);        // wave-uniform
            int qcol = base_q + col;
            float ps = 0.f;
            float p[4][4];
            #pragma unroll
            for (int t = 0; t < 4; ++t) {
                float amr[4] = {amv[t].x, amv[t].y, amv[t].z, amv[t].w};
                #pragma unroll
                for (int r = 0; r < 4; ++r) {
                    float s = St[qt][t][r] + amr[r];
                    if (!full) {
                        int kg = k0 + 16 * t + l4 * 4 + r;
                        s = (kg - qcol <= WIN) ? s : -INFINITY;
                    }
                    float e = __expf(s);
                    p[t][r] = e;
                    ps += e;
                }
            }
            lsum[qt] += ps;
            #pragma unroll
            for (int t = 0; t < 4; ++t) {
                uint2 w;
                w.x = pk_trunc(p[t][0], p[t][1]);
                w.y = pk_trunc(p[t][2], p[t][3]);
                *(uint2*)&sP[wave][qt][col * 72 + 16 * t + l4 * 4] = w;
            }
            short8 pa0 = *(short8*)&sP[wave][qt][col * 72 + l4 * 8];
            short8 pa1 = *(short8*)&sP[wave][qt][col * 72 + 32 + l4 * 8];
            #pragma unroll
            for (int dt = 0; dt < 4; ++dt) {
                O[qt][dt] = __builtin_amdgcn_mfma_f32_16x16x32_bf16(pa0, vf[dt][0], O[qt][dt], 0, 0, 0);
                O[qt][dt] = __builtin_amdgcn_mfma_f32_16x16x32_bf16(pa1, vf[dt][1], O[qt][dt], 0, 0, 0);
            }
        }
    }

    #pragma unroll
    for (int qt = 0; qt < 2; ++qt) {
        float l = lsum[qt];
        l += __shfl_xor(l, 16);
        l += __shfl_xor(l, 32);
        float linv = 1.0f / l;              // valid on lanes for q = col
        float lr[4];
        #pragma unroll
        for (int r = 0; r < 4; ++r) lr[r] = __shfl(linv, l4 * 4 + r);
        #pragma unroll
        for (int dt = 0; dt < 4; ++dt)
            #pragma unroll
            for (int r = 0; r < 4; ++r) {
                int s = q0 + qt * 64 + wave * 16 + l4 * 4 + r;
                Abf[(size_t)(b * SEQ_ + s) * HIDDEN + h * HD + dt * 16 + col] = f2bf(O[qt][dt][r] * lr[r]);
            }
    }
}

extern "C" void kernel_launch(void* const* d_in, const int* in_sizes, int n_in,
                              void* d_out, int out_size, void* d_ws, size_t ws_size,
                              hipStream_t stream) {
    const float* X  = (const float*)d_in[0];
    const float* am = (const float*)d_in[1];
    const float* Wq = (const float*)d_in[2];
    const float* bq = (const float*)d_in[3];
    const float* Wk = (const float*)d_in[4];
    const float* bk = (const float*)d_in[5];
    const float* Wv = (const float*)d_in[6];
    const float* bv = (const float*)d_in[7];
    const float* Wo = (const float*)d_in[8];
    float* out = (float*)d_out;

    const int M = BS_ * SEQ_;            // 4096
    u16* Qp  = (u16*)d_ws;                         // 8 MB
    u16* Kp  = Qp + (size_t)M * HIDDEN;            // 2 MB
    u16* Vtp = Kp + (size_t)M * 256;               // 2 MB
    u16* Xb  = Vtp + (size_t)M * 256;              // 8 MB
    u16* Wqb = Xb + (size_t)M * HIDDEN;            // 2 MB
    u16* Wkb = Wqb + (size_t)HIDDEN * HIDDEN;      // 0.5 MB
    u16* Wvb = Wkb + (size_t)256 * HIDDEN;         // 0.5 MB
    u16* Wob = Wvb + (size_t)256 * HIDDEN;         // 2 MB
    float* ams = (float*)(Wob + (size_t)HIDDEN * HIDDEN);  // 16 KB
    u16* Abf = Xb;  // alias: Xb consumed by gemm_qkv before attn writes Abf

    dim3 blk(256);
    cast6<<<dim3(4096, 6), blk, 0, stream>>>(X, Wq, Wk, Wv, Wo, am, Xb, Wqb, Wkb, Wvb, Wob, ams);
    gemm_qkv<<<dim3(12, 32), blk, 0, stream>>>(Xb, Wqb, Wkb, Wvb, bq, bk, bv, Qp, Kp, Vtp);
    attn_mfma<<<dim3(SEQ_ / 128, BS_ * NH), blk, 0, stream>>>(Qp, Kp, Vtp, ams, Abf);
    gemm_wo<<<dim3(8, 32), blk, 0, stream>>>(Abf, Wob, out);
}

// Round 6
// 203.578 us; speedup vs baseline: 5.6087x; 1.0710x over previous
//
#include <hip/hip_runtime.h>
#include <math.h>

#define HIDDEN 1024
#define NH 16
#define NKV 4
#define HD 64
#define BS_ 2
#define SEQ_ 2048
#define WIN 1534   // allowed iff k - q <= 1534

typedef unsigned short u16;
typedef short short8 __attribute__((ext_vector_type(8)));
typedef float f32x4 __attribute__((ext_vector_type(4)));
typedef u16 u16x4 __attribute__((ext_vector_type(4)));

__device__ __forceinline__ u16 f2bf(float f) {
    unsigned u = __float_as_uint(f);
    u += 0x7fff + ((u >> 16) & 1);      // RNE
    return (u16)(u >> 16);
}

// pack two f32 -> two bf16 (truncation) in ONE v_perm_b32
__device__ __forceinline__ unsigned pk_trunc(float lo, float hi) {
    return __builtin_amdgcn_perm(__float_as_uint(hi), __float_as_uint(lo), 0x07060302u);
}

__device__ __forceinline__ void async_ld16(const u16* g, u16* l) {
    __builtin_amdgcn_global_load_lds(
        (const __attribute__((address_space(1))) unsigned int*)g,
        (__attribute__((address_space(3))) unsigned int*)l, 16, 0, 0);
}

// ---------------- cast fp32 -> bf16 (X + 4 weights) and pre-scale amask ----------------
__global__ __launch_bounds__(256) void cast6(
    const float* __restrict__ x, const float* __restrict__ wq,
    const float* __restrict__ wk, const float* __restrict__ wv,
    const float* __restrict__ wo, const float* __restrict__ amask,
    u16* __restrict__ xb, u16* __restrict__ wqb, u16* __restrict__ wkb,
    u16* __restrict__ wvb, u16* __restrict__ wob, float* __restrict__ ams)
{
    int seg = blockIdx.y;
    int i = (blockIdx.x * 256 + threadIdx.x) * 4;
    if (seg == 5) {
        if (i >= BS_ * SEQ_) return;
        float4 v = *(const float4*)(amask + i);
        float4 o = make_float4(v.x * -10000.f, v.y * -10000.f, v.z * -10000.f, v.w * -10000.f);
        *(float4*)(ams + i) = o;
        return;
    }
    const float* srcs[5] = {x, wq, wk, wv, wo};
    u16* dsts[5] = {xb, wqb, wkb, wvb, wob};
    const int ns[5] = {4194304, 1048576, 262144, 262144, 1048576};
    if (i >= ns[seg]) return;
    float4 v = *(const float4*)(srcs[seg] + i);
    u16x4 o = {f2bf(v.x), f2bf(v.y), f2bf(v.z), f2bf(v.w)};
    *(u16x4*)(dsts[seg] + i) = o;
}

// ---------------- fused QKV MFMA GEMM ----------------
// grid (12, 32): bx<8 -> Q, bx<10 -> K, else V. 128x128 tile, BK=32.
// Q: bias+RoPE, pre-scaled by 1/8, bf16 head-major [b][h][s][64]
// K: bias+RoPE bf16 head-major; V: bias + bf16 V^T [b][hk][d][SEQ].
__global__ __launch_bounds__(256) void gemm_qkv(
    const u16* __restrict__ Xb, const u16* __restrict__ Wqb,
    const u16* __restrict__ Wkb, const u16* __restrict__ Wvb,
    const float* __restrict__ bq, const float* __restrict__ bk,
    const float* __restrict__ bv,
    u16* __restrict__ Qp, u16* __restrict__ Kp, u16* __restrict__ Vtp)
{
    __shared__ u16 sA[128 * 32];
    __shared__ u16 sB[128 * 32];
    int tid = threadIdx.x, lane = tid & 63, wave = tid >> 6;
    int col = lane & 15, l4 = lane >> 4;
    int bx = blockIdx.x, m0 = blockIdx.y * 128;
    const u16* Bsrc; const float* bias; int n0, mode;
    if (bx < 8)       { mode = 0; Bsrc = Wqb; bias = bq; n0 = bx * 128; }
    else if (bx < 10) { mode = 1; Bsrc = Wkb; bias = bk; n0 = (bx - 8) * 128; }
    else              { mode = 2; Bsrc = Wvb; bias = bv; n0 = (bx - 10) * 128; }

    int i0 = tid, i1 = tid + 256;
    const u16* ga0 = Xb + (size_t)(m0 + (i0 >> 2)) * HIDDEN + (i0 & 3) * 8;
    const u16* ga1 = Xb + (size_t)(m0 + (i1 >> 2)) * HIDDEN + (i1 & 3) * 8;
    const u16* gb0 = Bsrc + (size_t)(n0 + (i0 >> 2)) * HIDDEN + (i0 & 3) * 8;
    const u16* gb1 = Bsrc + (size_t)(n0 + (i1 >> 2)) * HIDDEN + (i1 & 3) * 8;
    u16* la0 = &sA[wave * 512];
    u16* la1 = &sA[2048 + wave * 512];
    u16* lb0 = &sB[wave * 512];
    u16* lb1 = &sB[2048 + wave * 512];

    f32x4 acc[4][4];
    #pragma unroll
    for (int i = 0; i < 4; ++i)
        #pragma unroll
        for (int j = 0; j < 4; ++j) acc[i][j] = (f32x4){0.f, 0.f, 0.f, 0.f};
    int mh = (wave & 1) * 64, nh = (wave >> 1) * 64;

    for (int k0 = 0; k0 < HIDDEN; k0 += 32) {
        __syncthreads();
        async_ld16(ga0, la0); async_ld16(ga1, la1);
        async_ld16(gb0, lb0); async_ld16(gb1, lb1);
        ga0 += 32; ga1 += 32; gb0 += 32; gb1 += 32;
        __syncthreads();
        short8 af[4], bf[4];
        #pragma unroll
        for (int mi = 0; mi < 4; ++mi)
            af[mi] = *(short8*)&sA[(mh + mi * 16 + col) * 32 + l4 * 8];
        #pragma unroll
        for (int ni = 0; ni < 4; ++ni)
            bf[ni] = *(short8*)&sB[(nh + ni * 16 + col) * 32 + l4 * 8];
        #pragma unroll
        for (int mi = 0; mi < 4; ++mi)
            #pragma unroll
            for (int ni = 0; ni < 4; ++ni)
                acc[mi][ni] = __builtin_amdgcn_mfma_f32_16x16x32_bf16(af[mi], bf[ni], acc[mi][ni], 0, 0, 0);
    }

    float bcol[4];
    #pragma unroll
    for (int ni = 0; ni < 4; ++ni) bcol[ni] = bias[n0 + nh + ni * 16 + col];

    if (mode == 2) {
        // V^T bf16: [b][hk][d][SEQ]; s contiguous over r -> b64 stores
        #pragma unroll
        for (int mi = 0; mi < 4; ++mi) {
            int m = m0 + mh + mi * 16 + l4 * 4;
            int b = m >> 11, s = m & 2047;
            #pragma unroll
            for (int ni = 0; ni < 4; ++ni) {
                int dg = n0 + nh + ni * 16 + col;
                u16x4 pk = {f2bf(acc[mi][ni][0] + bcol[ni]), f2bf(acc[mi][ni][1] + bcol[ni]),
                            f2bf(acc[mi][ni][2] + bcol[ni]), f2bf(acc[mi][ni][3] + bcol[ni])};
                *(u16x4*)&Vtp[((size_t)(b * NKV + (dg >> 6)) * HD + (dg & 63)) * SEQ_ + s] = pk;
            }
        }
    } else {
        int nheads = (mode == 0) ? NH : NKV;
        u16* outp = (mode == 0) ? Qp : Kp;
        float osc = (mode == 0) ? 0.125f : 1.0f;   // fold 1/sqrt(64) into Q
        int h = (n0 + nh) >> 6;   // 64-col wave-half = one head
        float invf[2];
        #pragma unroll
        for (int p = 0; p < 2; ++p)
            invf[p] = powf(10000.0f, -(float)(16 * p + col) * (1.0f / 32.0f));
        #pragma unroll
        for (int mi = 0; mi < 4; ++mi)
            #pragma unroll
            for (int r = 0; r < 4; ++r) {
                int m = m0 + mh + mi * 16 + l4 * 4 + r;
                int b = m >> 11, s = m & 2047;
                u16* q = outp + ((size_t)(b * nheads + h) * SEQ_ + s) * HD;
                #pragma unroll
                for (int p = 0; p < 2; ++p) {
                    float x0 = acc[mi][p][r] + bcol[p];
                    float x1 = acc[mi][p + 2][r] + bcol[p + 2];
                    float sn, cs;
                    __sincosf((float)s * invf[p], &sn, &cs);
                    q[16 * p + col]      = f2bf((x0 * cs - x1 * sn) * osc);
                    q[16 * p + col + 32] = f2bf((x0 * sn + x1 * cs) * osc);
                }
            }
    }
}

// ---------------- Wo MFMA GEMM: out[M,1024] f32 = Abf[M,1024] * Wob^T ----------------
__global__ __launch_bounds__(256) void gemm_wo(
    const u16* __restrict__ Abf, const u16* __restrict__ Wob, float* __restrict__ out)
{
    __shared__ u16 sA[128 * 32];
    __shared__ u16 sB[128 * 32];
    int tid = threadIdx.x, lane = tid & 63, wave = tid >> 6;
    int col = lane & 15, l4 = lane >> 4;
    int m0 = blockIdx.y * 128, n0 = blockIdx.x * 128;
    int i0 = tid, i1 = tid + 256;
    const u16* ga0 = Abf + (size_t)(m0 + (i0 >> 2)) * HIDDEN + (i0 & 3) * 8;
    const u16* ga1 = Abf + (size_t)(m0 + (i1 >> 2)) * HIDDEN + (i1 & 3) * 8;
    const u16* gb0 = Wob + (size_t)(n0 + (i0 >> 2)) * HIDDEN + (i0 & 3) * 8;
    const u16* gb1 = Wob + (size_t)(n0 + (i1 >> 2)) * HIDDEN + (i1 & 3) * 8;
    u16* la0 = &sA[wave * 512];
    u16* la1 = &sA[2048 + wave * 512];
    u16* lb0 = &sB[wave * 512];
    u16* lb1 = &sB[2048 + wave * 512];

    f32x4 acc[4][4];
    #pragma unroll
    for (int i = 0; i < 4; ++i)
        #pragma unroll
        for (int j = 0; j < 4; ++j) acc[i][j] = (f32x4){0.f, 0.f, 0.f, 0.f};
    int mh = (wave & 1) * 64, nh = (wave >> 1) * 64;

    for (int k0 = 0; k0 < HIDDEN; k0 += 32) {
        __syncthreads();
        async_ld16(ga0, la0); async_ld16(ga1, la1);
        async_ld16(gb0, lb0); async_ld16(gb1, lb1);
        ga0 += 32; ga1 += 32; gb0 += 32; gb1 += 32;
        __syncthreads();
        short8 af[4], bf[4];
        #pragma unroll
        for (int mi = 0; mi < 4; ++mi)
            af[mi] = *(short8*)&sA[(mh + mi * 16 + col) * 32 + l4 * 8];
        #pragma unroll
        for (int ni = 0; ni < 4; ++ni)
            bf[ni] = *(short8*)&sB[(nh + ni * 16 + col) * 32 + l4 * 8];
        #pragma unroll
        for (int mi = 0; mi < 4; ++mi)
            #pragma unroll
            for (int ni = 0; ni < 4; ++ni)
                acc[mi][ni] = __builtin_amdgcn_mfma_f32_16x16x32_bf16(af[mi], bf[ni], acc[mi][ni], 0, 0, 0);
    }
    #pragma unroll
    for (int mi = 0; mi < 4; ++mi)
        #pragma unroll
        for (int r = 0; r < 4; ++r) {
            int m = m0 + mh + mi * 16 + l4 * 4 + r;
            #pragma unroll
            for (int ni = 0; ni < 4; ++ni)
                out[(size_t)m * HIDDEN + n0 + nh + ni * 16 + col] = acc[mi][ni][r];
        }
}

// ---------------- MFMA flash attention v4: 512 threads, 8 waves x 16q ----------------
// 128 q/WG. Transposed-S; fixed (no-max) softmax; swizzled DMA staging.
// wave: qt = wave&1 (64-q half), ws = wave>>1 (16-q slice). Grid (16, 32).
__global__ __launch_bounds__(512) void attn_mfma(
    const u16* __restrict__ Qp, const u16* __restrict__ Kp,
    const u16* __restrict__ Vtp, const float* __restrict__ ams,
    u16* __restrict__ Abf)
{
    __shared__ u16 sK[4096];         // 64 keys x 64 d, chunk(row,c) holds logical c^(row&7)
    __shared__ u16 sVT[4096];        // 64 d x 64 keys, same swizzle
    __shared__ u16 sP[8][16 * 72];
    int tid = threadIdx.x;
    int lane = tid & 63, wave = tid >> 6;     // 0..7
    int col = lane & 15, l4 = lane >> 4;
    int qt = wave & 1, ws = wave >> 1;
    int qb = blockIdx.x, bh = blockIdx.y;
    int b = bh >> 4, h = bh & 15, hk = h >> 2;
    int q0 = qb * 128;
    int qbase = q0 + qt * 64 + ws * 16;       // this wave's 16 queries

    // Q fragment direct from global (B-operand: lane(col,l4) = Q[q=col][d=l4*8+j])
    const u16* qp = Qp + ((size_t)(b * NH + h) * SEQ_ + qbase + col) * HD;
    short8 qa0 = *(const short8*)(qp + l4 * 8);
    short8 qa1 = *(const short8*)(qp + 32 + l4 * 8);

    // staging: 512 threads x 16B = full 8KB tile per round.
    // dest chunk = tid; logical row = tid>>3, chunk-in-row = tid&7, src chunk = c^(row&7)
    int srow = tid >> 3;
    int swc = ((tid & 7) ^ (srow & 7)) * 8;
    const u16* Kbase = Kp + (size_t)(b * NKV + hk) * SEQ_ * HD;
    const u16* Vbase = Vtp + (size_t)(b * NKV + hk) * HD * SEQ_;
    const u16* pK = Kbase + (size_t)srow * HD + swc;
    const u16* pV = Vbase + (size_t)srow * SEQ_ + swc;
    u16* dK = &sK[wave * 512];
    u16* dV = &sVT[wave * 512];

    int sl0 = (l4 ^ (col & 7)) * 8;      // swizzled chunk offset, frag half 0
    int sl1 = sl0 ^ 32;                  // half 1 (logical chunk l4+4)

    f32x4 O[4];
    #pragma unroll
    for (int dt = 0; dt < 4; ++dt) O[dt] = (f32x4){0.f, 0.f, 0.f, 0.f};
    float lsum = 0.f;

    const float* amp = ams + b * SEQ_;
    int nk = min(SEQ_, q0 + 128 + WIN);
    int nkb = (nk + 63) >> 6;

    for (int kb = 0; kb < nkb; ++kb) {
        int k0 = kb * 64;
        __syncthreads();   // prior tile's reads complete
        async_ld16(pK + (size_t)k0 * HD, dK);
        async_ld16(pV + k0, dV);
        float4 amv[4];
        #pragma unroll
        for (int t = 0; t < 4; ++t)
            amv[t] = *(const float4*)(amp + k0 + 16 * t + l4 * 4);
        __syncthreads();   // DMA landed

        bool dead = k0 > qbase + 15 + WIN;   // wave-uniform
        if (!dead) {
            f32x4 St[4];
            #pragma unroll
            for (int t = 0; t < 4; ++t) St[t] = (f32x4){0.f, 0.f, 0.f, 0.f};
            #pragma unroll
            for (int t = 0; t < 4; ++t) {
                short8 kf0 = *(short8*)&sK[(t * 16 + col) * 64 + sl0];
                short8 kf1 = *(short8*)&sK[(t * 16 + col) * 64 + sl1];
                St[t] = __builtin_amdgcn_mfma_f32_16x16x32_bf16(kf0, qa0, St[t], 0, 0, 0);
                St[t] = __builtin_amdgcn_mfma_f32_16x16x32_bf16(kf1, qa1, St[t], 0, 0, 0);
            }
            bool full = (k0 + 63) <= (qbase + WIN);   // wave-uniform
            int qcol = qbase + col;
            float ps = 0.f;
            float p[4][4];
            #pragma unroll
            for (int t = 0; t < 4; ++t) {
                float amr[4] = {amv[t].x, amv[t].y, amv[t].z, amv[t].w};
                #pragma unroll
                for (int r = 0; r < 4; ++r) {
                    float s = St[t][r] + amr[r];
                    if (!full) {
                        int kg = k0 + 16 * t + l4 * 4 + r;
                        s = (kg - qcol <= WIN) ? s : -INFINITY;
                    }
                    float e = __expf(s);
                    p[t][r] = e;
                    ps += e;
                }
            }
            lsum += ps;
            #pragma unroll
            for (int t = 0; t < 4; ++t) {
                uint2 w;
                w.x = pk_trunc(p[t][0], p[t][1]);
                w.y = pk_trunc(p[t][2], p[t][3]);
                *(uint2*)&sP[wave][col * 72 + 16 * t + l4 * 4] = w;
            }
            short8 pa0 = *(short8*)&sP[wave][col * 72 + l4 * 8];
            short8 pa1 = *(short8*)&sP[wave][col * 72 + 32 + l4 * 8];
            #pragma unroll
            for (int dt = 0; dt < 4; ++dt) {
                short8 vf0 = *(short8*)&sVT[(dt * 16 + col) * 64 + sl0];
                short8 vf1 = *(short8*)&sVT[(dt * 16 + col) * 64 + sl1];
                O[dt] = __builtin_amdgcn_mfma_f32_16x16x32_bf16(pa0, vf0, O[dt], 0, 0, 0);
                O[dt] = __builtin_amdgcn_mfma_f32_16x16x32_bf16(pa1, vf1, O[dt], 0, 0, 0);
            }
        }
    }

    float l = lsum;
    l += __shfl_xor(l, 16);
    l += __shfl_xor(l, 32);
    float linv = 1.0f / l;               // full sum for q = qbase + col (all lanes)
    float lr[4];
    #pragma unroll
    for (int r = 0; r < 4; ++r) lr[r] = __shfl(linv, l4 * 4 + r);
    #pragma unroll
    for (int dt = 0; dt < 4; ++dt)
        #pragma unroll
        for (int r = 0; r < 4; ++r) {
            int s = qbase + l4 * 4 + r;
            Abf[(size_t)(b * SEQ_ + s) * HIDDEN + h * HD + dt * 16 + col] = f2bf(O[dt][r] * lr[r]);
        }
}

extern "C" void kernel_launch(void* const* d_in, const int* in_sizes, int n_in,
                              void* d_out, int out_size, void* d_ws, size_t ws_size,
                              hipStream_t stream) {
    const float* X  = (const float*)d_in[0];
    const float* am = (const float*)d_in[1];
    const float* Wq = (const float*)d_in[2];
    const float* bq = (const float*)d_in[3];
    const float* Wk = (const float*)d_in[4];
    const float* bk = (const float*)d_in[5];
    const float* Wv = (const float*)d_in[6];
    const float* bv = (const float*)d_in[7];
    const float* Wo = (const float*)d_in[8];
    float* out = (float*)d_out;

    const int M = BS_ * SEQ_;            // 4096
    u16* Qp  = (u16*)d_ws;                         // 8 MB
    u16* Kp  = Qp + (size_t)M * HIDDEN;            // 2 MB
    u16* Vtp = Kp + (size_t)M * 256;               // 2 MB
    u16* Xb  = Vtp + (size_t)M * 256;              // 8 MB
    u16* Wqb = Xb + (size_t)M * HIDDEN;            // 2 MB
    u16* Wkb = Wqb + (size_t)HIDDEN * HIDDEN;      // 0.5 MB
    u16* Wvb = Wkb + (size_t)256 * HIDDEN;         // 0.5 MB
    u16* Wob = Wvb + (size_t)256 * HIDDEN;         // 2 MB
    float* ams = (float*)(Wob + (size_t)HIDDEN * HIDDEN);  // 16 KB
    u16* Abf = Xb;  // alias: Xb consumed by gemm_qkv before attn writes Abf

    dim3 blk(256);
    cast6<<<dim3(4096, 6), blk, 0, stream>>>(X, Wq, Wk, Wv, Wo, am, Xb, Wqb, Wkb, Wvb, Wob, ams);
    gemm_qkv<<<dim3(12, 32), blk, 0, stream>>>(Xb, Wqb, Wkb, Wvb, bq, bk, bv, Qp, Kp, Vtp);
    attn_mfma<<<dim3(SEQ_ / 128, BS_ * NH), dim3(512), 0, stream>>>(Qp, Kp, Vtp, ams, Abf);
    gemm_wo<<<dim3(8, 32), blk, 0, stream>>>(Abf, Wob, out);
}

// Round 7
// 202.890 us; speedup vs baseline: 5.6277x; 1.0034x over previous
//
#include <hip/hip_runtime.h>
#include <math.h>

#define HIDDEN 1024
#define NH 16
#define NKV 4
#define HD 64
#define BS_ 2
#define SEQ_ 2048
#define WIN 1534   // allowed iff k - q <= 1534
#define LOG2E 1.4426950408889634f

typedef unsigned short u16;
typedef short short8 __attribute__((ext_vector_type(8)));
typedef float f32x4 __attribute__((ext_vector_type(4)));
typedef u16 u16x4 __attribute__((ext_vector_type(4)));

__device__ __forceinline__ u16 f2bf(float f) {
    unsigned u = __float_as_uint(f);
    u += 0x7fff + ((u >> 16) & 1);      // RNE
    return (u16)(u >> 16);
}

// pack two f32 -> two bf16 (truncation) in ONE v_perm_b32
__device__ __forceinline__ unsigned pk_trunc(float lo, float hi) {
    return __builtin_amdgcn_perm(__float_as_uint(hi), __float_as_uint(lo), 0x07060302u);
}

__device__ __forceinline__ void async_ld16(const u16* g, u16* l) {
    __builtin_amdgcn_global_load_lds(
        (const __attribute__((address_space(1))) unsigned int*)g,
        (__attribute__((address_space(3))) unsigned int*)l, 16, 0, 0);
}

// ---------------- cast fp32 -> bf16 (X + 4 weights) and pre-scale amask ----------------
// amask scaled by -10000*log2(e): attn uses exp2 directly.
__global__ __launch_bounds__(256) void cast6(
    const float* __restrict__ x, const float* __restrict__ wq,
    const float* __restrict__ wk, const float* __restrict__ wv,
    const float* __restrict__ wo, const float* __restrict__ amask,
    u16* __restrict__ xb, u16* __restrict__ wqb, u16* __restrict__ wkb,
    u16* __restrict__ wvb, u16* __restrict__ wob, float* __restrict__ ams)
{
    int seg = blockIdx.y;
    int i = (blockIdx.x * 256 + threadIdx.x) * 4;
    if (seg == 5) {
        if (i >= BS_ * SEQ_) return;
        const float sc = -10000.0f * LOG2E;
        float4 v = *(const float4*)(amask + i);
        float4 o = make_float4(v.x * sc, v.y * sc, v.z * sc, v.w * sc);
        *(float4*)(ams + i) = o;
        return;
    }
    const float* srcs[5] = {x, wq, wk, wv, wo};
    u16* dsts[5] = {xb, wqb, wkb, wvb, wob};
    const int ns[5] = {4194304, 1048576, 262144, 262144, 1048576};
    if (i >= ns[seg]) return;
    float4 v = *(const float4*)(srcs[seg] + i);
    u16x4 o = {f2bf(v.x), f2bf(v.y), f2bf(v.z), f2bf(v.w)};
    *(u16x4*)(dsts[seg] + i) = o;
}

// ---------------- fused QKV MFMA GEMM ----------------
// grid (12, 32): bx<8 -> Q, bx<10 -> K, else V. 128x128 tile, BK=32.
// Q: bias+RoPE, pre-scaled by 0.125*log2(e), bf16 head-major [b][h][s][64]
// K: bias+RoPE bf16 head-major; V: bias + bf16 V^T [b][hk][d][SEQ].
__global__ __launch_bounds__(256) void gemm_qkv(
    const u16* __restrict__ Xb, const u16* __restrict__ Wqb,
    const u16* __restrict__ Wkb, const u16* __restrict__ Wvb,
    const float* __restrict__ bq, const float* __restrict__ bk,
    const float* __restrict__ bv,
    u16* __restrict__ Qp, u16* __restrict__ Kp, u16* __restrict__ Vtp)
{
    __shared__ u16 sA[128 * 32];
    __shared__ u16 sB[128 * 32];
    int tid = threadIdx.x, lane = tid & 63, wave = tid >> 6;
    int col = lane & 15, l4 = lane >> 4;
    int bx = blockIdx.x, m0 = blockIdx.y * 128;
    const u16* Bsrc; const float* bias; int n0, mode;
    if (bx < 8)       { mode = 0; Bsrc = Wqb; bias = bq; n0 = bx * 128; }
    else if (bx < 10) { mode = 1; Bsrc = Wkb; bias = bk; n0 = (bx - 8) * 128; }
    else              { mode = 2; Bsrc = Wvb; bias = bv; n0 = (bx - 10) * 128; }

    int i0 = tid, i1 = tid + 256;
    const u16* ga0 = Xb + (size_t)(m0 + (i0 >> 2)) * HIDDEN + (i0 & 3) * 8;
    const u16* ga1 = Xb + (size_t)(m0 + (i1 >> 2)) * HIDDEN + (i1 & 3) * 8;
    const u16* gb0 = Bsrc + (size_t)(n0 + (i0 >> 2)) * HIDDEN + (i0 & 3) * 8;
    const u16* gb1 = Bsrc + (size_t)(n0 + (i1 >> 2)) * HIDDEN + (i1 & 3) * 8;
    u16* la0 = &sA[wave * 512];
    u16* la1 = &sA[2048 + wave * 512];
    u16* lb0 = &sB[wave * 512];
    u16* lb1 = &sB[2048 + wave * 512];

    f32x4 acc[4][4];
    #pragma unroll
    for (int i = 0; i < 4; ++i)
        #pragma unroll
        for (int j = 0; j < 4; ++j) acc[i][j] = (f32x4){0.f, 0.f, 0.f, 0.f};
    int mh = (wave & 1) * 64, nh = (wave >> 1) * 64;

    for (int k0 = 0; k0 < HIDDEN; k0 += 32) {
        __syncthreads();
        async_ld16(ga0, la0); async_ld16(ga1, la1);
        async_ld16(gb0, lb0); async_ld16(gb1, lb1);
        ga0 += 32; ga1 += 32; gb0 += 32; gb1 += 32;
        __syncthreads();
        short8 af[4], bf[4];
        #pragma unroll
        for (int mi = 0; mi < 4; ++mi)
            af[mi] = *(short8*)&sA[(mh + mi * 16 + col) * 32 + l4 * 8];
        #pragma unroll
        for (int ni = 0; ni < 4; ++ni)
            bf[ni] = *(short8*)&sB[(nh + ni * 16 + col) * 32 + l4 * 8];
        #pragma unroll
        for (int mi = 0; mi < 4; ++mi)
            #pragma unroll
            for (int ni = 0; ni < 4; ++ni)
                acc[mi][ni] = __builtin_amdgcn_mfma_f32_16x16x32_bf16(af[mi], bf[ni], acc[mi][ni], 0, 0, 0);
    }

    float bcol[4];
    #pragma unroll
    for (int ni = 0; ni < 4; ++ni) bcol[ni] = bias[n0 + nh + ni * 16 + col];

    if (mode == 2) {
        // V^T bf16: [b][hk][d][SEQ]; s contiguous over r -> b64 stores
        #pragma unroll
        for (int mi = 0; mi < 4; ++mi) {
            int m = m0 + mh + mi * 16 + l4 * 4;
            int b = m >> 11, s = m & 2047;
            #pragma unroll
            for (int ni = 0; ni < 4; ++ni) {
                int dg = n0 + nh + ni * 16 + col;
                u16x4 pk = {f2bf(acc[mi][ni][0] + bcol[ni]), f2bf(acc[mi][ni][1] + bcol[ni]),
                            f2bf(acc[mi][ni][2] + bcol[ni]), f2bf(acc[mi][ni][3] + bcol[ni])};
                *(u16x4*)&Vtp[((size_t)(b * NKV + (dg >> 6)) * HD + (dg & 63)) * SEQ_ + s] = pk;
            }
        }
    } else {
        int nheads = (mode == 0) ? NH : NKV;
        u16* outp = (mode == 0) ? Qp : Kp;
        float osc = (mode == 0) ? 0.125f * LOG2E : 1.0f;   // fold 1/sqrt(64)*log2e into Q
        int h = (n0 + nh) >> 6;   // 64-col wave-half = one head
        float invf[2];
        #pragma unroll
        for (int p = 0; p < 2; ++p)
            invf[p] = powf(10000.0f, -(float)(16 * p + col) * (1.0f / 32.0f));
        #pragma unroll
        for (int mi = 0; mi < 4; ++mi)
            #pragma unroll
            for (int r = 0; r < 4; ++r) {
                int m = m0 + mh + mi * 16 + l4 * 4 + r;
                int b = m >> 11, s = m & 2047;
                u16* q = outp + ((size_t)(b * nheads + h) * SEQ_ + s) * HD;
                #pragma unroll
                for (int p = 0; p < 2; ++p) {
                    float x0 = acc[mi][p][r] + bcol[p];
                    float x1 = acc[mi][p + 2][r] + bcol[p + 2];
                    float sn, cs;
                    __sincosf((float)s * invf[p], &sn, &cs);
                    q[16 * p + col]      = f2bf((x0 * cs - x1 * sn) * osc);
                    q[16 * p + col + 32] = f2bf((x0 * sn + x1 * cs) * osc);
                }
            }
    }
}

// ---------------- Wo MFMA GEMM: out[M,1024] f32 = Abf[M,1024] * Wob^T ----------------
__global__ __launch_bounds__(256) void gemm_wo(
    const u16* __restrict__ Abf, const u16* __restrict__ Wob, float* __restrict__ out)
{
    __shared__ u16 sA[128 * 32];
    __shared__ u16 sB[128 * 32];
    int tid = threadIdx.x, lane = tid & 63, wave = tid >> 6;
    int col = lane & 15, l4 = lane >> 4;
    int m0 = blockIdx.y * 128, n0 = blockIdx.x * 128;
    int i0 = tid, i1 = tid + 256;
    const u16* ga0 = Abf + (size_t)(m0 + (i0 >> 2)) * HIDDEN + (i0 & 3) * 8;
    const u16* ga1 = Abf + (size_t)(m0 + (i1 >> 2)) * HIDDEN + (i1 & 3) * 8;
    const u16* gb0 = Wob + (size_t)(n0 + (i0 >> 2)) * HIDDEN + (i0 & 3) * 8;
    const u16* gb1 = Wob + (size_t)(n0 + (i1 >> 2)) * HIDDEN + (i1 & 3) * 8;
    u16* la0 = &sA[wave * 512];
    u16* la1 = &sA[2048 + wave * 512];
    u16* lb0 = &sB[wave * 512];
    u16* lb1 = &sB[2048 + wave * 512];

    f32x4 acc[4][4];
    #pragma unroll
    for (int i = 0; i < 4; ++i)
        #pragma unroll
        for (int j = 0; j < 4; ++j) acc[i][j] = (f32x4){0.f, 0.f, 0.f, 0.f};
    int mh = (wave & 1) * 64, nh = (wave >> 1) * 64;

    for (int k0 = 0; k0 < HIDDEN; k0 += 32) {
        __syncthreads();
        async_ld16(ga0, la0); async_ld16(ga1, la1);
        async_ld16(gb0, lb0); async_ld16(gb1, lb1);
        ga0 += 32; ga1 += 32; gb0 += 32; gb1 += 32;
        __syncthreads();
        short8 af[4], bf[4];
        #pragma unroll
        for (int mi = 0; mi < 4; ++mi)
            af[mi] = *(short8*)&sA[(mh + mi * 16 + col) * 32 + l4 * 8];
        #pragma unroll
        for (int ni = 0; ni < 4; ++ni)
            bf[ni] = *(short8*)&sB[(nh + ni * 16 + col) * 32 + l4 * 8];
        #pragma unroll
        for (int mi = 0; mi < 4; ++mi)
            #pragma unroll
            for (int ni = 0; ni < 4; ++ni)
                acc[mi][ni] = __builtin_amdgcn_mfma_f32_16x16x32_bf16(af[mi], bf[ni], acc[mi][ni], 0, 0, 0);
    }
    #pragma unroll
    for (int mi = 0; mi < 4; ++mi)
        #pragma unroll
        for (int r = 0; r < 4; ++r) {
            int m = m0 + mh + mi * 16 + l4 * 4 + r;
            #pragma unroll
            for (int ni = 0; ni < 4; ++ni)
                out[(size_t)m * HIDDEN + n0 + nh + ni * 16 + col] = acc[mi][ni][r];
        }
}

// ---------------- MFMA flash attention v5: 64 q/WG, 8 waves = 4 q-slices x 2 key-halves ----------------
// Grid (32, 32) = 1024 WGs -> 4 WG/CU, 32 waves/CU ceiling.
// Wave (ws, kh): 16 q x 32 keys per staged 64-key tile. End-of-kernel LDS combine of key-halves.
__global__ __launch_bounds__(512, 8) void attn_mfma(
    const u16* __restrict__ Qp, const u16* __restrict__ Kp,
    const u16* __restrict__ Vtp, const float* __restrict__ ams,
    u16* __restrict__ Abf)
{
    __shared__ u16 sKV[8192];        // sK = [0:4096] (64 keys x 64 d), sVT = [4096:8192] (64 d x 64 keys)
    __shared__ u16 sP[8][16 * 72];   // per-wave P scratch (keys 0..31 local)
    u16* sK = sKV;
    u16* sVT = sKV + 4096;
    int tid = threadIdx.x;
    int lane = tid & 63, wave = tid >> 6;     // 0..7
    int col = lane & 15, l4 = lane >> 4;
    int ws = wave & 3, kh = wave >> 2;
    int qb = blockIdx.x, bh = blockIdx.y;
    int b = bh >> 4, h = bh & 15, hk = h >> 2;
    int q0 = qb * 64;
    int qbase = q0 + ws * 16;                 // this wave's 16 queries

    // Q fragment direct from global (B-operand for QK^T: lane(col,l4) = Q[q=col][d=l4*8+j])
    const u16* qp = Qp + ((size_t)(b * NH + h) * SEQ_ + qbase + col) * HD;
    short8 qa0 = *(const short8*)(qp + l4 * 8);
    short8 qa1 = *(const short8*)(qp + 32 + l4 * 8);

    // staging: 512 threads x 16B = full 8KB K tile + 8KB V tile per round, XOR-swizzled chunks
    int srow = tid >> 3;
    int swc = ((tid & 7) ^ (srow & 7)) * 8;
    const u16* Kbase = Kp + (size_t)(b * NKV + hk) * SEQ_ * HD;
    const u16* Vbase = Vtp + (size_t)(b * NKV + hk) * HD * SEQ_;
    const u16* pK = Kbase + (size_t)srow * HD + swc;
    const u16* pV = Vbase + (size_t)srow * SEQ_ + swc;
    u16* dK = &sK[wave * 512];
    u16* dV = &sVT[wave * 512];

    int sl0 = (l4 ^ (col & 7)) * 8;                 // kf chunk, d-half 0
    int sl1 = sl0 ^ 32;                             // d-half 1
    int slv = ((kh * 4 + l4) ^ (col & 7)) * 8;      // vf chunk, this wave's key-half

    f32x4 O[4];
    #pragma unroll
    for (int dt = 0; dt < 4; ++dt) O[dt] = (f32x4){0.f, 0.f, 0.f, 0.f};
    float lsum = 0.f;

    const float* amp = ams + b * SEQ_;
    int nk = min(SEQ_, q0 + 64 + WIN);
    int nkb = (nk + 63) >> 6;

    for (int kb = 0; kb < nkb; ++kb) {
        int k0 = kb * 64;
        __syncthreads();   // prior tile's reads complete
        async_ld16(pK + (size_t)k0 * HD, dK);
        async_ld16(pV + k0, dV);
        float4 amv[2];
        #pragma unroll
        for (int tt = 0; tt < 2; ++tt)
            amv[tt] = *(const float4*)(amp + k0 + kh * 32 + tt * 16 + l4 * 4);
        __syncthreads();   // DMA landed

        bool dead = (k0 + kh * 32) > (qbase + 15 + WIN);   // wave-uniform
        if (!dead) {
            f32x4 St[2];
            St[0] = (f32x4){0.f, 0.f, 0.f, 0.f};
            St[1] = (f32x4){0.f, 0.f, 0.f, 0.f};
            #pragma unroll
            for (int tt = 0; tt < 2; ++tt) {
                int t = kh * 2 + tt;
                short8 kf0 = *(short8*)&sK[(t * 16 + col) * 64 + sl0];
                short8 kf1 = *(short8*)&sK[(t * 16 + col) * 64 + sl1];
                St[tt] = __builtin_amdgcn_mfma_f32_16x16x32_bf16(kf0, qa0, St[tt], 0, 0, 0);
                St[tt] = __builtin_amdgcn_mfma_f32_16x16x32_bf16(kf1, qa1, St[tt], 0, 0, 0);
            }
            bool full = (k0 + kh * 32 + 31) <= (qbase + WIN);   // wave-uniform
            int qcol = qbase + col;
            float ps = 0.f;
            float p[2][4];
            #pragma unroll
            for (int tt = 0; tt < 2; ++tt) {
                float amr[4] = {amv[tt].x, amv[tt].y, amv[tt].z, amv[tt].w};
                #pragma unroll
                for (int r = 0; r < 4; ++r) {
                    float s = St[tt][r] + amr[r];
                    if (!full) {
                        int kg = k0 + kh * 32 + tt * 16 + l4 * 4 + r;
                        s = (kg - qcol <= WIN) ? s : -INFINITY;
                    }
                    float e = __builtin_amdgcn_exp2f(s);   // scores pre-scaled by log2e
                    p[tt][r] = e;
                    ps += e;
                }
            }
            lsum += ps;
            #pragma unroll
            for (int tt = 0; tt < 2; ++tt) {
                uint2 w;
                w.x = pk_trunc(p[tt][0], p[tt][1]);
                w.y = pk_trunc(p[tt][2], p[tt][3]);
                *(uint2*)&sP[wave][col * 72 + 16 * tt + l4 * 4] = w;
            }
            // PV over this wave's 32 keys: one K=32 MFMA per d-tile
            short8 pa = *(short8*)&sP[wave][col * 72 + l4 * 8];
            #pragma unroll
            for (int dt = 0; dt < 4; ++dt) {
                short8 vf = *(short8*)&sVT[(dt * 16 + col) * 64 + slv];
                O[dt] = __builtin_amdgcn_mfma_f32_16x16x32_bf16(pa, vf, O[dt], 0, 0, 0);
            }
        }
    }

    // ---- combine key-halves (kh=0 <- kh=1) through LDS overlay ----
    float l = lsum;
    l += __shfl_xor(l, 16);
    l += __shfl_xor(l, 32);          // all lanes: partial sum for q = qbase + col
    __syncthreads();                  // loop reads done; sKV/sP reusable
    float* sO = (float*)sKV;          // [ws][16 q][64 d] f32 = 16 KB
    float* sL = (float*)&sP[0][0];    // [ws][16]
    if (kh == 1) {
        #pragma unroll
        for (int dt = 0; dt < 4; ++dt)
            #pragma unroll
            for (int r = 0; r < 4; ++r)
                sO[(ws * 16 + l4 * 4 + r) * 64 + dt * 16 + col] = O[dt][r];
        if (l4 == 0) sL[ws * 16 + col] = l;
    }
    __syncthreads();
    if (kh == 0) {
        float ltot = l + sL[ws * 16 + col];
        float linv = 1.0f / ltot;
        float lr[4];
        #pragma unroll
        for (int r = 0; r < 4; ++r) lr[r] = __shfl(linv, l4 * 4 + r);
        #pragma unroll
        for (int dt = 0; dt < 4; ++dt)
            #pragma unroll
            for (int r = 0; r < 4; ++r) {
                float o = O[dt][r] + sO[(ws * 16 + l4 * 4 + r) * 64 + dt * 16 + col];
                int s = qbase + l4 * 4 + r;
                Abf[(size_t)(b * SEQ_ + s) * HIDDEN + h * HD + dt * 16 + col] = f2bf(o * lr[r]);
            }
    }
}

extern "C" void kernel_launch(void* const* d_in, const int* in_sizes, int n_in,
                              void* d_out, int out_size, void* d_ws, size_t ws_size,
                              hipStream_t stream) {
    const float* X  = (const float*)d_in[0];
    const float* am = (const float*)d_in[1];
    const float* Wq = (const float*)d_in[2];
    const float* bq = (const float*)d_in[3];
    const float* Wk = (const float*)d_in[4];
    const float* bk = (const float*)d_in[5];
    const float* Wv = (const float*)d_in[6];
    const float* bv = (const float*)d_in[7];
    const float* Wo = (const float*)d_in[8];
    float* out = (float*)d_out;

    const int M = BS_ * SEQ_;            // 4096
    u16* Qp  = (u16*)d_ws;                         // 8 MB
    u16* Kp  = Qp + (size_t)M * HIDDEN;            // 2 MB
    u16* Vtp = Kp + (size_t)M * 256;               // 2 MB
    u16* Xb  = Vtp + (size_t)M * 256;              // 8 MB
    u16* Wqb = Xb + (size_t)M * HIDDEN;            // 2 MB
    u16* Wkb = Wqb + (size_t)HIDDEN * HIDDEN;      // 0.5 MB
    u16* Wvb = Wkb + (size_t)256 * HIDDEN;         // 0.5 MB
    u16* Wob = Wvb + (size_t)256 * HIDDEN;         // 2 MB
    float* ams = (float*)(Wob + (size_t)HIDDEN * HIDDEN);  // 16 KB
    u16* Abf = Xb;  // alias: Xb consumed by gemm_qkv before attn writes Abf

    dim3 blk(256);
    cast6<<<dim3(4096, 6), blk, 0, stream>>>(X, Wq, Wk, Wv, Wo, am, Xb, Wqb, Wkb, Wvb, Wob, ams);
    gemm_qkv<<<dim3(12, 32), blk, 0, stream>>>(Xb, Wqb, Wkb, Wvb, bq, bk, bv, Qp, Kp, Vtp);
    attn_mfma<<<dim3(SEQ_ / 64, BS_ * NH), dim3(512), 0, stream>>>(Qp, Kp, Vtp, ams, Abf);
    gemm_wo<<<dim3(8, 32), blk, 0, stream>>>(Abf, Wob, out);
}